// Round 3
// baseline (680.420 us; speedup 1.0000x reference)
//
#include <hip/hip_runtime.h>
#include <math.h>

#define NANCH 1614
#define A1 1176
#define A2 1470
#define KSPLIT 4
#define N_D1E (16*128*196)   // 401408 elements of d1

// ---------------- workspace layout (float offsets) ----------------
#define OFF_D1 0
#define OFF_D2 401408
#define OFF_D3 501760
#define OFF_SC 534528
#define OFF_PF 560352
#define OFF_P  691424
#define OFF_INT 1152416          // ints: anchors 1614*4, topidx 64 (6528 slots)
#define OFF_BIG 1158944          // union region, 16B aligned
// MFMA-path union members (float offsets from OFF_BIG):
#define SZ_AT 3211264            // 16*196*2048 ushort = this many floats
#define SZ_BW 1179648            // 9*128*2048 ushort  = this many floats
#define OFF_ATH (OFF_BIG)
#define OFF_ATL (OFF_ATH + SZ_AT)
#define OFF_BWH (OFF_ATL + SZ_AT)
#define OFF_BWL (OFF_BWH + SZ_BW)
#define OFF_PM  (OFF_BWL + SZ_BW)
#define SZ_PM   3612672          // 9*3136*128 floats
#define TOTAL_MFMA_F (OFF_PM + SZ_PM)          // 13,553,440 floats = 54.2 MB
#define TOTAL_FALLBACK_F (OFF_BIG + KSPLIT*N_D1E)

// output layout (floats): resnet_out[3200] | concat_logits[3200] | part_logits[12800] | top_idx[64] | top_n_prob[64]
#define OUT_CONCAT 3200
#define OUT_PART   6400
#define OUT_TIDX   19200
#define OUT_TPROB  19264

typedef __attribute__((ext_vector_type(8))) short short8;
typedef __attribute__((ext_vector_type(4))) float f32x4;

__device__ __forceinline__ unsigned short bf16_rn(float f) {
    unsigned u = __float_as_uint(f);
    unsigned r = u + 0x7fffu + ((u >> 16) & 1u);   // RN-even
    return (unsigned short)(r >> 16);
}
__device__ __forceinline__ float bf16_to_f(unsigned short h) {
    return __uint_as_float(((unsigned)h) << 16);
}

// ---------------- anchors (replicates _gen_edge_anchors in f64) ----------------
__global__ void anchor_kernel(int* __restrict__ anc) {
    int i = blockIdx.x * 256 + threadIdx.x;
    if (i >= NANCH) return;
    int stride, n, sgroup, j;
    double size;
    if (i < A1)      { stride = 32;  size = 48.0;  n = 14; j = i;      sgroup = 0; }
    else if (i < A2) { stride = 64;  size = 96.0;  n = 7;  j = i - A1; sgroup = 0; }
    else             { stride = 128; size = 192.0; n = 4;  j = i - A2; sgroup = 1; }
    int cells = n * n;
    int combo = j / cells, cell = j % cells;
    int sc_i = combo / 3, ar_i = combo % 3;
    double sc;
    if (sgroup == 0) sc = pow(2.0, (double)(sc_i + 1) / 3.0);
    else             sc = (sc_i == 0) ? 1.0 : pow(2.0, (double)sc_i / 3.0);
    double ar = (ar_i == 0) ? 0.667 : ((ar_i == 1) ? 1.0 : 1.5);
    int y = cell / n, x = cell % n;
    double cy = (double)y * stride + stride / 2.0;
    double cx = (double)x * stride + stride / 2.0;
    double sq = sqrt(ar);
    double h = size * sc / sq, w = size * sc * sq;
    anc[i*4+0] = (int)(cy - h/2.0 + 224.0);
    anc[i*4+1] = (int)(cx - w/2.0 + 224.0);
    anc[i*4+2] = (int)(cy + h/2.0 + 224.0);
    anc[i*4+3] = (int)(cx + w/2.0 + 224.0);
}

// ================= MFMA d1 path =================
// rpn[b][ic][s] f32 -> At_hi/lo[b][s][ic] bf16 (transposed split), via LDS tile
__launch_bounds__(256)
__global__ void split_rpn_t(const float* __restrict__ rpn,
                            unsigned short* __restrict__ ath, unsigned short* __restrict__ atl) {
    __shared__ float T[32*196];
    int b = blockIdx.x >> 6, icb = blockIdx.x & 63;   // 64 ic-blocks of 32
    int tid = threadIdx.x;
    for (int idx = tid; idx < 32*196; idx += 256) {
        int i = idx / 196, s = idx % 196;
        T[idx] = rpn[((size_t)(b*2048 + icb*32 + i))*196 + s];
    }
    __syncthreads();
    for (int idx = tid; idx < 32*196; idx += 256) {
        int s = idx >> 5, i = idx & 31;
        float f = T[i*196 + s];
        unsigned short hi = bf16_rn(f);
        unsigned short lo = bf16_rn(f - bf16_to_f(hi));
        size_t o = ((size_t)(b*196 + s))*2048 + icb*32 + i;
        ath[o] = hi; atl[o] = lo;
    }
}

// w1[oc][ic][tap] f32 -> Bw_hi/lo[tap][oc][ic] bf16
__global__ void split_w(const float* __restrict__ w1,
                        unsigned short* __restrict__ bwh, unsigned short* __restrict__ bwl) {
    int idx = blockIdx.x * 256 + threadIdx.x;
    if (idx >= 9*128*2048) return;
    int tap = idx / (128*2048);
    int rem = idx % (128*2048);
    int oc = rem >> 11, ic = rem & 2047;
    float f = w1[((size_t)(oc*2048 + ic))*9 + tap];
    unsigned short hi = bf16_rn(f);
    unsigned short lo = bf16_rn(f - bf16_to_f(hi));
    bwh[idx] = hi; bwl[idx] = lo;
}

// GEMM: partM[tap][row=(b,s)][oc] = sum_ic A[row][tap,ic] * B[tap,ic][oc]
// grid = 98 M-blocks(32 rows) x 9 taps; 256 thr = 4 waves (2 Mwr x 2 Nwc), wave tile 16x64
__launch_bounds__(256)
__global__ void d1_mfma(const unsigned short* __restrict__ ath, const unsigned short* __restrict__ atl,
                        const unsigned short* __restrict__ bwh, const unsigned short* __restrict__ bwl,
                        float* __restrict__ partM) {
    __shared__ unsigned short Ah[32*40], Al[32*40], Bh[128*40], Bl[128*40]; // pad 32->40 shorts
    int tid = threadIdx.x;
    int mb = blockIdx.x % 98, tap = blockIdx.x / 98;
    int dy = tap/3 - 1, dx = tap%3 - 1;
    int wave = tid >> 6, lane = tid & 63;
    int wr = wave >> 1, wc = wave & 1;
    int lg = lane >> 4, lr = lane & 15;

    // A staging: 1 load/thread per step: (row, half, slot)
    int ar = tid >> 3, ahalf = (tid >> 2) & 1, aslot = tid & 3;
    int grow = mb*32 + ar;
    int b = grow / 196, s = grow % 196;
    int y = s / 14, x = s % 14;
    int ys = y + dy, xs = x + dx;
    bool avalid = (ys >= 0) && (ys < 14) && (xs >= 0) && (xs < 14);
    const unsigned short* asrc = (ahalf ? atl : ath)
        + ((size_t)(b*196 + (avalid ? (ys*14 + xs) : 0)))*2048 + aslot*8;
    unsigned short* adst = (ahalf ? Al : Ah) + ar*40 + aslot*8;

    // B staging: 4 loads/thread per step
    const unsigned short* bsrc[4]; unsigned short* bdst[4];
#pragma unroll
    for (int rep = 0; rep < 4; ++rep) {
        int idx = rep*256 + tid;
        int half = idx >> 9, u = idx & 511, oc = u >> 2, slot = u & 3;
        bsrc[rep] = (half ? bwl : bwh) + ((size_t)(tap*128 + oc))*2048 + slot*8;
        bdst[rep] = (half ? Bl : Bh) + oc*40 + slot*8;
    }

    f32x4 acc[4];
#pragma unroll
    for (int f = 0; f < 4; ++f) acc[f] = (f32x4){0.f, 0.f, 0.f, 0.f};
    const short8 zer = {0,0,0,0,0,0,0,0};

    short8 ga, gb[4];
    ga = avalid ? *(const short8*)(asrc) : zer;
#pragma unroll
    for (int rep = 0; rep < 4; ++rep) gb[rep] = *(const short8*)(bsrc[rep]);

    for (int step = 0; step < 64; ++step) {
        __syncthreads();                       // previous step's ds_reads done
        *(short8*)adst = ga;
#pragma unroll
        for (int rep = 0; rep < 4; ++rep) *(short8*)bdst[rep] = gb[rep];
        __syncthreads();
        if (step + 1 < 64) {                   // prefetch next step during compute
            int ic0 = (step + 1) * 32;
            ga = avalid ? *(const short8*)(asrc + ic0) : zer;
#pragma unroll
            for (int rep = 0; rep < 4; ++rep) gb[rep] = *(const short8*)(bsrc[rep] + ic0);
        }
        short8 a_h = *(const short8*)&Ah[(wr*16 + lr)*40 + lg*8];
        short8 a_l = *(const short8*)&Al[(wr*16 + lr)*40 + lg*8];
#pragma unroll
        for (int f = 0; f < 4; ++f) {
            int oc = wc*64 + f*16 + lr;
            short8 b_h = *(const short8*)&Bh[oc*40 + lg*8];
            short8 b_l = *(const short8*)&Bl[oc*40 + lg*8];
            // 3-pass split-bf16: hi*hi + hi*lo + lo*hi (lo*lo dropped, <=2^-18 rel)
            acc[f] = __builtin_amdgcn_mfma_f32_16x16x32_bf16(a_h, b_h, acc[f], 0, 0, 0);
            acc[f] = __builtin_amdgcn_mfma_f32_16x16x32_bf16(a_h, b_l, acc[f], 0, 0, 0);
            acc[f] = __builtin_amdgcn_mfma_f32_16x16x32_bf16(a_l, b_h, acc[f], 0, 0, 0);
        }
    }
    // C/D layout (m89-verified): col = lane&15, row = (lane>>4)*4 + reg
#pragma unroll
    for (int f = 0; f < 4; ++f) {
        int oc = wc*64 + f*16 + lr;
#pragma unroll
        for (int r = 0; r < 4; ++r) {
            int row = mb*32 + wr*16 + lg*4 + r;
            partM[((size_t)tap*3136 + row)*128 + oc] = acc[f][r];
        }
    }
}

__global__ void d1_combine(const float* __restrict__ partM, const float* __restrict__ b1,
                           float* __restrict__ d1) {
    int idx = blockIdx.x*256 + threadIdx.x;
    if (idx >= 3136*128) return;
    int oc = idx & 127, row = idx >> 7;
    float s = 0.f;
#pragma unroll
    for (int t = 0; t < 9; ++t) s += partM[(size_t)t*3136*128 + idx];
    int b = row / 196, sp = row % 196;
    d1[(b*128 + oc)*196 + sp] = fmaxf(s + b1[oc], 0.f);
}

// ================= fp32 fallback d1 path (used if ws_size too small) =================
__launch_bounds__(256)
__global__ void conv_d1_part(const float* __restrict__ rpn, const float* __restrict__ w1,
                             float* __restrict__ part) {
    __shared__ float lin[8*256];
    __shared__ float lwT[576];
    int tid = threadIdx.x;
    int ks = blockIdx.x & 3;
    int tile = (blockIdx.x >> 2) & 15;
    int b = blockIdx.x >> 6;
    int py = tid >> 4, px = tid & 15;
    bool pvalid = (py >= 1) && (py <= 14) && (px >= 1) && (px <= 14);
    int in_off = (b*2048)*196 + (py-1)*14 + (px-1);
    const float* wb = w1 + tile*8*18432;
    int s = tid, y = s / 14, x = s % 14;
    bool active = s < 196;
    float acc[8];
#pragma unroll
    for (int o = 0; o < 8; ++o) acc[o] = 0.f;
    float pv[8]; float wv[3];
    int c0 = ks * 64;
#pragma unroll
    for (int i = 0; i < 8; ++i) pv[i] = pvalid ? rpn[in_off + (c0*8 + i)*196] : 0.f;
#pragma unroll
    for (int r = 0; r < 3; ++r) {
        int u = tid + r*256;
        if (u < 576) { int oc = u/72, rem = u%72; wv[r] = wb[oc*18432 + c0*72 + rem]; }
    }
    for (int c = 0; c < 64; ++c) {
#pragma unroll
        for (int i = 0; i < 8; ++i) lin[i*256 + tid] = pv[i];
#pragma unroll
        for (int r = 0; r < 3; ++r) {
            int u = tid + r*256;
            if (u < 576) { int oc = u/72, rem = u%72; lwT[rem*8 + oc] = wv[r]; }
        }
        __syncthreads();
        if (c + 1 < 64) {
            int icb = (c0 + c + 1) * 8;
#pragma unroll
            for (int i = 0; i < 8; ++i) pv[i] = pvalid ? rpn[in_off + (icb + i)*196] : 0.f;
#pragma unroll
            for (int r = 0; r < 3; ++r) {
                int u = tid + r*256;
                if (u < 576) { int oc = u/72, rem = u%72; wv[r] = wb[oc*18432 + icb*9 + rem]; }
            }
        }
        if (active) {
#pragma unroll
            for (int ic = 0; ic < 8; ++ic) {
                int base = ic*256 + y*16 + x;
                float p[9];
                p[0]=lin[base+0];  p[1]=lin[base+1];  p[2]=lin[base+2];
                p[3]=lin[base+16]; p[4]=lin[base+17]; p[5]=lin[base+18];
                p[6]=lin[base+32]; p[7]=lin[base+33]; p[8]=lin[base+34];
#pragma unroll
                for (int k = 0; k < 9; ++k) {
                    const float4 wa  = *(const float4*)&lwT[(ic*9 + k)*8];
                    const float4 wb4 = *(const float4*)&lwT[(ic*9 + k)*8 + 4];
                    acc[0] += p[k]*wa.x;  acc[1] += p[k]*wa.y;
                    acc[2] += p[k]*wa.z;  acc[3] += p[k]*wa.w;
                    acc[4] += p[k]*wb4.x; acc[5] += p[k]*wb4.y;
                    acc[6] += p[k]*wb4.z; acc[7] += p[k]*wb4.w;
                }
            }
        }
        __syncthreads();
    }
    if (active) {
#pragma unroll
        for (int o = 0; o < 8; ++o) {
            int oc = tile*8 + o;
            part[ks*N_D1E + (b*128 + oc)*196 + s] = acc[o];
        }
    }
}

__global__ void d1_reduce(const float* __restrict__ part, const float* __restrict__ b1,
                          float* __restrict__ d1) {
    int idx = blockIdx.x * 256 + threadIdx.x;
    if (idx >= N_D1E) return;
    int oc = (idx / 196) & 127;
    float s = part[idx] + part[idx + N_D1E] + part[idx + 2*N_D1E] + part[idx + 3*N_D1E];
    d1[idx] = fmaxf(s + b1[oc], 0.f);
}

// ---------------- generic 128->128 3x3 s2 p1 conv, relu (d2, d3) ----------------
__global__ void conv_s2_kernel(const float* __restrict__ in, const float* __restrict__ w,
                               const float* __restrict__ bias, float* __restrict__ out,
                               int H, int W, int HO, int WO, int total) {
    int idx = blockIdx.x * 256 + threadIdx.x;
    if (idx >= total) return;
    int xo = idx % WO; int t = idx / WO; int yo = t % HO; t /= HO; int oc = t % 128; int b = t / 128;
    float acc = bias[oc];
    const float* ip = in + (b*128)*H*W;
    const float* wp = w + oc*128*9;
    for (int ic = 0; ic < 128; ++ic) {
        const float* iic = ip + ic*H*W;
        const float* wic = wp + ic*9;
#pragma unroll
        for (int dy = 0; dy < 3; ++dy) {
            int iy = 2*yo - 1 + dy;
            if (iy < 0 || iy >= H) continue;
#pragma unroll
            for (int dx = 0; dx < 3; ++dx) {
                int ix = 2*xo - 1 + dx;
                if (ix < 0 || ix >= W) continue;
                acc += iic[iy*W + ix] * wic[dy*3 + dx];
            }
        }
    }
    out[idx] = fmaxf(acc, 0.f);
}

// ---------------- tidy 1x1 convs -> concatenated score vector ----------------
__global__ void tidy_kernel(const float* __restrict__ d1, const float* __restrict__ d2, const float* __restrict__ d3,
                            const float* __restrict__ t1w, const float* __restrict__ t1b,
                            const float* __restrict__ t2w, const float* __restrict__ t2b,
                            const float* __restrict__ t3w, const float* __restrict__ t3b,
                            float* __restrict__ scores) {
    int idx = blockIdx.x * 256 + threadIdx.x;
    if (idx >= 16*NANCH) return;
    int b = idx / NANCH, i = idx % NANCH;
    const float* src; const float* tw; const float* tb; int S, c, s;
    if (i < A1)      { c = i/196;           s = i%196;        src = d1 + b*128*196 + s; S = 196; tw = t1w; tb = t1b; }
    else if (i < A2) { int j = i - A1; c = j/49; s = j%49;    src = d2 + b*128*49  + s; S = 49;  tw = t2w; tb = t2b; }
    else             { int j = i - A2; c = j/16; s = j%16;    src = d3 + b*128*16  + s; S = 16;  tw = t3w; tb = t3b; }
    float acc = tb[c];
    const float* wr = tw + c*128;
    for (int ic = 0; ic < 128; ++ic) acc += src[ic*S] * wr[ic];
    scores[idx] = acc;
}

// ---------------- hard NMS (one block per batch) ----------------
__launch_bounds__(256)
__global__ void nms_kernel(const float* __restrict__ scores, const int* __restrict__ anc,
                           int* __restrict__ topidx, float* __restrict__ out) {
    __shared__ float s[NANCH];
    __shared__ float by0[NANCH], bx0[NANCH], by1[NANCH], bx1[NANCH], ar[NANCH];
    __shared__ float rv[256]; __shared__ int ri[256];
    __shared__ int sel[4];
    int b = blockIdx.x, tid = threadIdx.x;
    for (int j = tid; j < NANCH; j += 256) {
        s[j] = scores[b*NANCH + j];
        float y0 = (float)anc[j*4+0], x0 = (float)anc[j*4+1];
        float y1 = (float)anc[j*4+2], x1 = (float)anc[j*4+3];
        by0[j] = y0; bx0[j] = x0; by1[j] = y1; bx1[j] = x1;
        ar[j] = (y1 - y0) * (x1 - x0);
    }
    __syncthreads();
    for (int k = 0; k < 4; ++k) {
        float bv = -INFINITY; int bi = NANCH;
        for (int j = tid; j < NANCH; j += 256) {
            float v = s[j];
            if (v > bv) { bv = v; bi = j; }
        }
        rv[tid] = bv; ri[tid] = bi;
        __syncthreads();
        for (int off = 128; off > 0; off >>= 1) {
            if (tid < off) {
                float v2 = rv[tid+off]; int i2 = ri[tid+off];
                if (v2 > rv[tid] || (v2 == rv[tid] && i2 < ri[tid])) { rv[tid] = v2; ri[tid] = i2; }
            }
            __syncthreads();
        }
        int i = ri[0];
        if (tid == 0) sel[k] = i;
        float a0 = by0[i], a1 = bx0[i], a2 = by1[i], a3 = bx1[i], ai = ar[i];
        for (int j = tid; j < NANCH; j += 256) {
            float yy0 = fmaxf(by0[j], a0), xx0 = fmaxf(bx0[j], a1);
            float yy1 = fminf(by1[j], a2), xx1 = fminf(bx1[j], a3);
            float inter = fmaxf(yy1 - yy0, 0.f) * fmaxf(xx1 - xx0, 0.f);
            float iou = inter / (ar[j] + ai - inter);
            if (!(iou < 0.25f)) s[j] = -INFINITY;
        }
        if (tid == 0) s[i] = -INFINITY;
        __syncthreads();
    }
    if (tid < 4) {
        int i = sel[tid];
        topidx[b*4 + tid] = i;
        out[OUT_TIDX  + b*4 + tid] = (float)i;
        out[OUT_TPROB + b*4 + tid] = scores[b*NANCH + i];
    }
}

// ---------------- bilinear sampler: only the 49x49 pixels the 7x7/s32 conv reads ----------------
__device__ __forceinline__ float fetchpix(const float* img, int Y, int X) {
    if (Y >= 224 && Y < 672 && X >= 224 && X < 672) return img[(Y - 224)*448 + (X - 224)];
    return 0.f;
}

__global__ void sampler_kernel(const float* __restrict__ x, const int* __restrict__ anc,
                               const int* __restrict__ topidx, float* __restrict__ P) {
    int crop = blockIdx.x;
    int b = crop >> 2;
    int idx = topidx[crop];
    float y0 = (float)anc[idx*4+0], x0 = (float)anc[idx*4+1];
    float y1 = (float)anc[idx*4+2], x1 = (float)anc[idx*4+3];
    float dy = y1 - y0 - 1.0f, dx = x1 - x0 - 1.0f;
    const float* imgb = x + b*3*448*448;
    for (int u = threadIdx.x; u < 7203; u += 256) {
        int c = u / 2401; int rem = u % 2401;
        int rid = rem / 49, cid = rem % 49;
        int oy = rid/7, ky = rid%7, ox = cid/7, kx = cid%7;
        int rr = 32*oy - 3 + ky, cc = 32*ox - 3 + kx;
        float val = 0.f;
        if (rr >= 0 && cc >= 0) {
            float ty = (float)rr / 223.0f;
            float ys = __fadd_rn(y0, __fmul_rn(ty, dy));
            int yi0 = (int)floorf(ys); yi0 = yi0 < 0 ? 0 : (yi0 > 895 ? 895 : yi0);
            int yi1 = (yi0 + 1 > 895) ? 895 : yi0 + 1;
            float wy = ys - (float)yi0;
            float tx = (float)cc / 223.0f;
            float xs = __fadd_rn(x0, __fmul_rn(tx, dx));
            int xi0 = (int)floorf(xs); xi0 = xi0 < 0 ? 0 : (xi0 > 895 ? 895 : xi0);
            int xi1 = (xi0 + 1 > 895) ? 895 : xi0 + 1;
            float wx = xs - (float)xi0;
            const float* img = imgb + c*448*448;
            float p00 = fetchpix(img, yi0, xi0), p10 = fetchpix(img, yi1, xi0);
            float p01 = fetchpix(img, yi0, xi1), p11 = fetchpix(img, yi1, xi1);
            float r0 = p00 + (p10 - p00)*wy;
            float r1 = p01 + (p11 - p01)*wy;
            val = r0 + (r1 - r0)*wx;
        }
        int pos = oy*7 + ox, kk = c*49 + ky*7 + kx;
        P[crop*7203 + pos*147 + kk] = val;
    }
}

// ---------------- feat conv as GEMM (K=147) fused with relu+mean ----------------
__launch_bounds__(256)
__global__ void feat_gemm_kernel(const float* __restrict__ P, const float* __restrict__ fw,
                                 const float* __restrict__ fb, float* __restrict__ pf) {
    __shared__ float lp[49*148];
    int crop = blockIdx.x >> 3, tile = blockIdx.x & 7;
    int oc = tile*256 + threadIdx.x;
    for (int u = threadIdx.x; u < 7203; u += 256)
        lp[(u/147)*148 + (u%147)] = P[crop*7203 + u];
    __syncthreads();
    float s[49];
#pragma unroll
    for (int p = 0; p < 49; ++p) s[p] = 0.f;
    const float* wr = fw + oc*147;
    for (int kc = 0; kc < 36; ++kc) {
        float w0 = wr[kc*4], w1 = wr[kc*4+1], w2 = wr[kc*4+2], w3 = wr[kc*4+3];
#pragma unroll
        for (int p = 0; p < 49; ++p) {
            float4 v = *(const float4*)&lp[p*148 + kc*4];
            s[p] += v.x*w0 + v.y*w1 + v.z*w2 + v.w*w3;
        }
    }
    {
        float w0 = wr[144], w1 = wr[145], w2 = wr[146];
#pragma unroll
        for (int p = 0; p < 49; ++p)
            s[p] += lp[p*148+144]*w0 + lp[p*148+145]*w1 + lp[p*148+146]*w2;
    }
    float bias = fb[oc], acc = 0.f;
#pragma unroll
    for (int p = 0; p < 49; ++p) acc += fmaxf(s[p] + bias, 0.f);
    pf[crop*2048 + oc] = acc / 49.0f;
}

// ---------------- part logits ----------------
__global__ void partcls_kernel(const float* __restrict__ pf, const float* __restrict__ pw,
                               const float* __restrict__ pb, float* __restrict__ out) {
    int o = blockIdx.x; int crop = o / 200, cls = o % 200;
    int lane = threadIdx.x;
    const float* a = pf + crop*2048; const float* w = pw + cls*2048;
    float sum = 0.f;
    for (int k = lane; k < 2048; k += 64) sum += a[k] * w[k];
#pragma unroll
    for (int off = 32; off > 0; off >>= 1) sum += __shfl_down(sum, off);
    if (lane == 0) out[OUT_PART + o] = sum + pb[cls];
}

// ---------------- concat logits: one block per class, 16 batches per block ----------------
__launch_bounds__(256)
__global__ void concat_kernel(const float* __restrict__ pf, const float* __restrict__ feature,
                              const float* __restrict__ cw, const float* __restrict__ cb,
                              float* __restrict__ out) {
    __shared__ float red[4][16];
    int j = blockIdx.x, tid = threadIdx.x;
    const float* w = cw + (size_t)j*10240;
    float acc[16];
#pragma unroll
    for (int b = 0; b < 16; ++b) acc[b] = 0.f;
    for (int k = tid; k < 10240; k += 256) {
        float wk = w[k];
        const float* v; int stride;
        if (k < 8192) { v = pf + k; stride = 8192; }
        else          { v = feature + (k - 8192); stride = 2048; }
#pragma unroll
        for (int b = 0; b < 16; ++b) acc[b] += v[b*stride] * wk;
    }
#pragma unroll
    for (int b = 0; b < 16; ++b) {
        float s2 = acc[b];
#pragma unroll
        for (int off = 32; off > 0; off >>= 1) s2 += __shfl_down(s2, off);
        if ((tid & 63) == 0) red[tid >> 6][b] = s2;
    }
    __syncthreads();
    if (tid < 16)
        out[OUT_CONCAT + tid*200 + j] = red[0][tid] + red[1][tid] + red[2][tid] + red[3][tid] + cb[j];
}

extern "C" void kernel_launch(void* const* d_in, const int* in_sizes, int n_in,
                              void* d_out, int out_size, void* d_ws, size_t ws_size,
                              hipStream_t stream) {
    const float* x    = (const float*)d_in[0];
    const float* rpn  = (const float*)d_in[1];
    const float* feat = (const float*)d_in[2];
    const float* rout = (const float*)d_in[3];
    const float* d1w  = (const float*)d_in[4];
    const float* d1b  = (const float*)d_in[5];
    const float* d2w  = (const float*)d_in[6];
    const float* d2b  = (const float*)d_in[7];
    const float* d3w  = (const float*)d_in[8];
    const float* d3b  = (const float*)d_in[9];
    const float* t1w  = (const float*)d_in[10];
    const float* t1b  = (const float*)d_in[11];
    const float* t2w  = (const float*)d_in[12];
    const float* t2b  = (const float*)d_in[13];
    const float* t3w  = (const float*)d_in[14];
    const float* t3b  = (const float*)d_in[15];
    const float* fw   = (const float*)d_in[16];
    const float* fbb  = (const float*)d_in[17];
    const float* pw   = (const float*)d_in[18];
    const float* pb   = (const float*)d_in[19];
    const float* cw   = (const float*)d_in[20];
    const float* cb   = (const float*)d_in[21];
    float* out = (float*)d_out;
    float* wsf = (float*)d_ws;
    float* d1  = wsf + OFF_D1;
    float* d2  = wsf + OFF_D2;
    float* d3  = wsf + OFF_D3;
    float* sc  = wsf + OFF_SC;
    float* pfb = wsf + OFF_PF;
    float* P   = wsf + OFF_P;
    int* anc    = (int*)(wsf + OFF_INT);
    int* topidx = anc + NANCH*4;

    // resnet_out passthrough
    hipMemcpyAsync(out, rout, 3200*sizeof(float), hipMemcpyDeviceToDevice, stream);

    anchor_kernel<<<7, 256, 0, stream>>>(anc);

    bool use_mfma = ws_size >= (size_t)TOTAL_MFMA_F * sizeof(float);
    if (use_mfma) {
        unsigned short* ath = (unsigned short*)(wsf + OFF_ATH);
        unsigned short* atl = (unsigned short*)(wsf + OFF_ATL);
        unsigned short* bwh = (unsigned short*)(wsf + OFF_BWH);
        unsigned short* bwl = (unsigned short*)(wsf + OFF_BWL);
        float* pm = wsf + OFF_PM;
        split_rpn_t<<<1024, 256, 0, stream>>>(rpn, ath, atl);
        split_w<<<9216, 256, 0, stream>>>(d1w, bwh, bwl);
        d1_mfma<<<98*9, 256, 0, stream>>>(ath, atl, bwh, bwl, pm);
        d1_combine<<<(3136*128 + 255)/256, 256, 0, stream>>>(pm, d1b, d1);
    } else {
        float* part = wsf + OFF_BIG;
        conv_d1_part<<<16*16*KSPLIT, 256, 0, stream>>>(rpn, d1w, part);
        d1_reduce<<<(N_D1E + 255)/256, 256, 0, stream>>>(part, d1b, d1);
    }

    conv_s2_kernel<<<392, 256, 0, stream>>>(d1, d2w, d2b, d2, 14, 14, 7, 7, 16*128*49);
    conv_s2_kernel<<<128, 256, 0, stream>>>(d2, d3w, d3b, d3, 7, 7, 4, 4, 16*128*16);
    tidy_kernel<<<101, 256, 0, stream>>>(d1, d2, d3, t1w, t1b, t2w, t2b, t3w, t3b, sc);
    nms_kernel<<<16, 256, 0, stream>>>(sc, anc, topidx, out);
    sampler_kernel<<<64, 256, 0, stream>>>(x, anc, topidx, P);
    feat_gemm_kernel<<<512, 256, 0, stream>>>(P, fw, fbb, pfb);
    partcls_kernel<<<12800, 64, 0, stream>>>(pfb, pw, pb, out);
    concat_kernel<<<200, 256, 0, stream>>>(pfb, feat, cw, cb, out);
}

// Round 5
// 412.449 us; speedup vs baseline: 1.6497x; 1.6497x over previous
//
#include <hip/hip_runtime.h>
#include <math.h>

#define NANCH 1614
#define A1 1176
#define A2 1470
#define KSPLIT 4
#define N_D1E (16*128*196)   // 401408 elements of d1

// ---------------- workspace layout (float offsets) ----------------
#define OFF_D1 0
#define OFF_D2 401408
#define OFF_D3 501760
#define OFF_SC 534528
#define OFF_PF 560352
#define OFF_P  691424
#define OFF_INT 1152416          // ints: anchors 1614*4, topidx 64 (6528 slots)
#define OFF_BIG 1158944          // union region, 16B aligned
// MFMA-path union members (float offsets from OFF_BIG):
#define SZ_AT 3211264            // 16*196*2048 ushort = this many floats
#define SZ_BW 1179648            // 9*128*2048 ushort  = this many floats
#define OFF_ATH (OFF_BIG)
#define OFF_ATL (OFF_ATH + SZ_AT)
#define OFF_BWH (OFF_ATL + SZ_AT)
#define OFF_BWL (OFF_BWH + SZ_BW)
#define OFF_PM  (OFF_BWL + SZ_BW)
#define SZ_PM   3612672          // 9*3136*128 floats
#define TOTAL_MFMA_F (OFF_PM + SZ_PM)          // 13,553,440 floats = 54.2 MB
// After d1 is finalized, the OFF_BIG region is dead -> reuse for d2/d3 partials.
#define N_D2E (16*128*49)        // 100352
#define N_D3E (16*128*16)        // 32768
#define OFF_P2 OFF_BIG
#define OFF_P3 (OFF_BIG + 4*N_D2E)

// output layout (floats): resnet_out[3200] | concat_logits[3200] | part_logits[12800] | top_idx[64] | top_n_prob[64]
#define OUT_CONCAT 3200
#define OUT_PART   6400
#define OUT_TIDX   19200
#define OUT_TPROB  19264

typedef __attribute__((ext_vector_type(8))) short short8;
typedef __attribute__((ext_vector_type(4))) float f32x4;

__device__ __forceinline__ unsigned short bf16_rn(float f) {
    unsigned u = __float_as_uint(f);
    unsigned r = u + 0x7fffu + ((u >> 16) & 1u);   // RN-even
    return (unsigned short)(r >> 16);
}
__device__ __forceinline__ float bf16_to_f(unsigned short h) {
    return __uint_as_float(((unsigned)h) << 16);
}

// ---------------- anchors (replicates _gen_edge_anchors in f64) ----------------
__global__ void anchor_kernel(int* __restrict__ anc) {
    int i = blockIdx.x * 256 + threadIdx.x;
    if (i >= NANCH) return;
    int stride, n, sgroup, j;
    double size;
    if (i < A1)      { stride = 32;  size = 48.0;  n = 14; j = i;      sgroup = 0; }
    else if (i < A2) { stride = 64;  size = 96.0;  n = 7;  j = i - A1; sgroup = 0; }
    else             { stride = 128; size = 192.0; n = 4;  j = i - A2; sgroup = 1; }
    int cells = n * n;
    int combo = j / cells, cell = j % cells;
    int sc_i = combo / 3, ar_i = combo % 3;
    double sc;
    if (sgroup == 0) sc = pow(2.0, (double)(sc_i + 1) / 3.0);
    else             sc = (sc_i == 0) ? 1.0 : pow(2.0, (double)sc_i / 3.0);
    double ar = (ar_i == 0) ? 0.667 : ((ar_i == 1) ? 1.0 : 1.5);
    int y = cell / n, x = cell % n;
    double cy = (double)y * stride + stride / 2.0;
    double cx = (double)x * stride + stride / 2.0;
    double sq = sqrt(ar);
    double h = size * sc / sq, w = size * sc * sq;
    anc[i*4+0] = (int)(cy - h/2.0 + 224.0);
    anc[i*4+1] = (int)(cx - w/2.0 + 224.0);
    anc[i*4+2] = (int)(cy + h/2.0 + 224.0);
    anc[i*4+3] = (int)(cx + w/2.0 + 224.0);
}

// ================= MFMA d1 path =================
// T row stride 197 (odd): transpose-read phase hits 32 distinct banks (was 4-way @196)
__launch_bounds__(256)
__global__ void split_rpn_t(const float* __restrict__ rpn,
                            unsigned short* __restrict__ ath, unsigned short* __restrict__ atl) {
    __shared__ float T[32*197];
    int b = blockIdx.x >> 6, icb = blockIdx.x & 63;   // 64 ic-blocks of 32
    int tid = threadIdx.x;
    for (int idx = tid; idx < 32*196; idx += 256) {
        int i = idx / 196, s = idx % 196;
        T[i*197 + s] = rpn[((size_t)(b*2048 + icb*32 + i))*196 + s];
    }
    __syncthreads();
    for (int idx = tid; idx < 32*196; idx += 256) {
        int s = idx >> 5, i = idx & 31;
        float f = T[i*197 + s];
        unsigned short hi = bf16_rn(f);
        unsigned short lo = bf16_rn(f - bf16_to_f(hi));
        size_t o = ((size_t)(b*196 + s))*2048 + icb*32 + i;
        ath[o] = hi; atl[o] = lo;
    }
}

__global__ void split_w(const float* __restrict__ w1,
                        unsigned short* __restrict__ bwh, unsigned short* __restrict__ bwl) {
    int idx = blockIdx.x * 256 + threadIdx.x;
    if (idx >= 9*128*2048) return;
    int tap = idx / (128*2048);
    int rem = idx % (128*2048);
    int oc = rem >> 11, ic = rem & 2047;
    float f = w1[((size_t)(oc*2048 + ic))*9 + tap];
    unsigned short hi = bf16_rn(f);
    unsigned short lo = bf16_rn(f - bf16_to_f(hi));
    bwh[idx] = hi; bwl[idx] = lo;
}

// GEMM: partM[tap][row=(b,s)][oc] = sum_ic A[row][tap,ic] * B[tap,ic][oc]
__launch_bounds__(256)
__global__ void d1_mfma(const unsigned short* __restrict__ ath, const unsigned short* __restrict__ atl,
                        const unsigned short* __restrict__ bwh, const unsigned short* __restrict__ bwl,
                        float* __restrict__ partM) {
    __shared__ unsigned short Ah[32*40], Al[32*40], Bh[128*40], Bl[128*40]; // pad 32->40 shorts
    int tid = threadIdx.x;
    int mb = blockIdx.x % 98, tap = blockIdx.x / 98;
    int dy = tap/3 - 1, dx = tap%3 - 1;
    int wave = tid >> 6, lane = tid & 63;
    int wr = wave >> 1, wc = wave & 1;
    int lg = lane >> 4, lr = lane & 15;

    int ar = tid >> 3, ahalf = (tid >> 2) & 1, aslot = tid & 3;
    int grow = mb*32 + ar;
    int b = grow / 196, s = grow % 196;
    int y = s / 14, x = s % 14;
    int ys = y + dy, xs = x + dx;
    bool avalid = (ys >= 0) && (ys < 14) && (xs >= 0) && (xs < 14);
    const unsigned short* asrc = (ahalf ? atl : ath)
        + ((size_t)(b*196 + (avalid ? (ys*14 + xs) : 0)))*2048 + aslot*8;
    unsigned short* adst = (ahalf ? Al : Ah) + ar*40 + aslot*8;

    const unsigned short* bsrc[4]; unsigned short* bdst[4];
#pragma unroll
    for (int rep = 0; rep < 4; ++rep) {
        int idx = rep*256 + tid;
        int half = idx >> 9, u = idx & 511, oc = u >> 2, slot = u & 3;
        bsrc[rep] = (half ? bwl : bwh) + ((size_t)(tap*128 + oc))*2048 + slot*8;
        bdst[rep] = (half ? Bl : Bh) + oc*40 + slot*8;
    }

    f32x4 acc[4];
#pragma unroll
    for (int f = 0; f < 4; ++f) acc[f] = (f32x4){0.f, 0.f, 0.f, 0.f};
    const short8 zer = {0,0,0,0,0,0,0,0};

    short8 ga, gb[4];
    ga = avalid ? *(const short8*)(asrc) : zer;
#pragma unroll
    for (int rep = 0; rep < 4; ++rep) gb[rep] = *(const short8*)(bsrc[rep]);

    for (int step = 0; step < 64; ++step) {
        __syncthreads();
        *(short8*)adst = ga;
#pragma unroll
        for (int rep = 0; rep < 4; ++rep) *(short8*)bdst[rep] = gb[rep];
        __syncthreads();
        if (step + 1 < 64) {
            int ic0 = (step + 1) * 32;
            ga = avalid ? *(const short8*)(asrc + ic0) : zer;
#pragma unroll
            for (int rep = 0; rep < 4; ++rep) gb[rep] = *(const short8*)(bsrc[rep] + ic0);
        }
        short8 a_h = *(const short8*)&Ah[(wr*16 + lr)*40 + lg*8];
        short8 a_l = *(const short8*)&Al[(wr*16 + lr)*40 + lg*8];
#pragma unroll
        for (int f = 0; f < 4; ++f) {
            int oc = wc*64 + f*16 + lr;
            short8 b_h = *(const short8*)&Bh[oc*40 + lg*8];
            short8 b_l = *(const short8*)&Bl[oc*40 + lg*8];
            acc[f] = __builtin_amdgcn_mfma_f32_16x16x32_bf16(a_h, b_h, acc[f], 0, 0, 0);
            acc[f] = __builtin_amdgcn_mfma_f32_16x16x32_bf16(a_h, b_l, acc[f], 0, 0, 0);
            acc[f] = __builtin_amdgcn_mfma_f32_16x16x32_bf16(a_l, b_h, acc[f], 0, 0, 0);
        }
    }
#pragma unroll
    for (int f = 0; f < 4; ++f) {
        int oc = wc*64 + f*16 + lr;
#pragma unroll
        for (int r = 0; r < 4; ++r) {
            int row = mb*32 + wr*16 + lg*4 + r;
            partM[((size_t)tap*3136 + row)*128 + oc] = acc[f][r];
        }
    }
}

__global__ void d1_combine(const float* __restrict__ partM, const float* __restrict__ b1,
                           float* __restrict__ d1) {
    int idx = blockIdx.x*256 + threadIdx.x;
    if (idx >= 3136*128) return;
    int oc = idx & 127, row = idx >> 7;
    float s = 0.f;
#pragma unroll
    for (int t = 0; t < 9; ++t) s += partM[(size_t)t*3136*128 + idx];
    int b = row / 196, sp = row % 196;
    d1[(b*128 + oc)*196 + sp] = fmaxf(s + b1[oc], 0.f);
}

// ================= fp32 fallback d1 path (used if ws_size too small) =================
__launch_bounds__(256)
__global__ void conv_d1_part(const float* __restrict__ rpn, const float* __restrict__ w1,
                             float* __restrict__ part) {
    __shared__ float lin[8*256];
    __shared__ float lwT[576];
    int tid = threadIdx.x;
    int ks = blockIdx.x & 3;
    int tile = (blockIdx.x >> 2) & 15;
    int b = blockIdx.x >> 6;
    int py = tid >> 4, px = tid & 15;
    bool pvalid = (py >= 1) && (py <= 14) && (px >= 1) && (px <= 14);
    int in_off = (b*2048)*196 + (py-1)*14 + (px-1);
    const float* wb = w1 + tile*8*18432;
    int s = tid, y = s / 14, x = s % 14;
    bool active = s < 196;
    float acc[8];
#pragma unroll
    for (int o = 0; o < 8; ++o) acc[o] = 0.f;
    float pv[8]; float wv[3];
    int c0 = ks * 64;
#pragma unroll
    for (int i = 0; i < 8; ++i) pv[i] = pvalid ? rpn[in_off + (c0*8 + i)*196] : 0.f;
#pragma unroll
    for (int r = 0; r < 3; ++r) {
        int u = tid + r*256;
        if (u < 576) { int oc = u/72, rem = u%72; wv[r] = wb[oc*18432 + c0*72 + rem]; }
    }
    for (int c = 0; c < 64; ++c) {
#pragma unroll
        for (int i = 0; i < 8; ++i) lin[i*256 + tid] = pv[i];
#pragma unroll
        for (int r = 0; r < 3; ++r) {
            int u = tid + r*256;
            if (u < 576) { int oc = u/72, rem = u%72; lwT[rem*8 + oc] = wv[r]; }
        }
        __syncthreads();
        if (c + 1 < 64) {
            int icb = (c0 + c + 1) * 8;
#pragma unroll
            for (int i = 0; i < 8; ++i) pv[i] = pvalid ? rpn[in_off + (icb + i)*196] : 0.f;
#pragma unroll
            for (int r = 0; r < 3; ++r) {
                int u = tid + r*256;
                if (u < 576) { int oc = u/72, rem = u%72; wv[r] = wb[oc*18432 + icb*9 + rem]; }
            }
        }
        if (active) {
#pragma unroll
            for (int ic = 0; ic < 8; ++ic) {
                int base = ic*256 + y*16 + x;
                float p[9];
                p[0]=lin[base+0];  p[1]=lin[base+1];  p[2]=lin[base+2];
                p[3]=lin[base+16]; p[4]=lin[base+17]; p[5]=lin[base+18];
                p[6]=lin[base+32]; p[7]=lin[base+33]; p[8]=lin[base+34];
#pragma unroll
                for (int k = 0; k < 9; ++k) {
                    const float4 wa  = *(const float4*)&lwT[(ic*9 + k)*8];
                    const float4 wb4 = *(const float4*)&lwT[(ic*9 + k)*8 + 4];
                    acc[0] += p[k]*wa.x;  acc[1] += p[k]*wa.y;
                    acc[2] += p[k]*wa.z;  acc[3] += p[k]*wa.w;
                    acc[4] += p[k]*wb4.x; acc[5] += p[k]*wb4.y;
                    acc[6] += p[k]*wb4.z; acc[7] += p[k]*wb4.w;
                }
            }
        }
        __syncthreads();
    }
    if (active) {
#pragma unroll
        for (int o = 0; o < 8; ++o) {
            int oc = tile*8 + o;
            part[ks*N_D1E + (b*128 + oc)*196 + s] = acc[o];
        }
    }
}

__global__ void d1_reduce(const float* __restrict__ part, const float* __restrict__ b1,
                          float* __restrict__ d1) {
    int idx = blockIdx.x * 256 + threadIdx.x;
    if (idx >= N_D1E) return;
    int oc = (idx / 196) & 127;
    float s = part[idx] + part[idx + N_D1E] + part[idx + 2*N_D1E] + part[idx + 3*N_D1E];
    d1[idx] = fmaxf(s + b1[oc], 0.f);
}

// ================= d2: 128->128 3x3 s2 p1, 14x14 -> 7x7 (partial over ic) =================
// grid = 16 b * 4 octiles(32 oc) * 4 ksplit(32 ic); 256 thr: g=t>>6 (8-oc group), s=t&63 (<49)
__launch_bounds__(256)
__global__ void conv_d2_part(const float* __restrict__ d1, const float* __restrict__ w2,
                             float* __restrict__ part) {
    __shared__ float lin[8*320];    // [ic][py*20+px], stride 20 breaks 32-float bank alias
    __shared__ float lwT[72*32];    // [(ic*9+tap)][oc_l(32)]
    int tid = threadIdx.x;
    int ks = blockIdx.x & 3;
    int octile = (blockIdx.x >> 2) & 3;
    int b = blockIdx.x >> 4;
    int py = tid >> 4, px = tid & 15;
    bool pvalid = (py >= 1) && (py <= 14) && (px >= 1) && (px <= 14);
    int in_base = (b*128)*196 + (py-1)*14 + (px-1);
    int g = tid >> 6, s = tid & 63;
    int yo = s / 7, xo = s % 7;
    bool active = s < 49;
    const float* wb = w2 + (octile*32)*1152 + ks*288;   // + oc_l*1152 + chunk*72 + rem

    float acc[8];
#pragma unroll
    for (int o = 0; o < 8; ++o) acc[o] = 0.f;
    float pv[8], wv[9];
    // prologue: chunk 0 (ic = ks*32 .. +8)
#pragma unroll
    for (int i = 0; i < 8; ++i) pv[i] = pvalid ? d1[in_base + (ks*32 + i)*196] : 0.f;
#pragma unroll
    for (int r = 0; r < 9; ++r) {
        int u = tid + r*256; int oc_l = u/72, rem = u%72;
        wv[r] = wb[oc_l*1152 + rem];
    }
    for (int c = 0; c < 4; ++c) {
#pragma unroll
        for (int i = 0; i < 8; ++i) lin[i*320 + py*20 + px] = pv[i];
#pragma unroll
        for (int r = 0; r < 9; ++r) {
            int u = tid + r*256; int oc_l = u/72, rem = u%72;
            lwT[rem*32 + oc_l] = wv[r];
        }
        __syncthreads();
        if (c + 1 < 4) {
            int ic0 = ks*32 + (c+1)*8;
#pragma unroll
            for (int i = 0; i < 8; ++i) pv[i] = pvalid ? d1[in_base + (ic0 + i)*196] : 0.f;
#pragma unroll
            for (int r = 0; r < 9; ++r) {
                int u = tid + r*256; int oc_l = u/72, rem = u%72;
                wv[r] = wb[oc_l*1152 + (c+1)*72 + rem];
            }
        }
        if (active) {
#pragma unroll
            for (int ic = 0; ic < 8; ++ic) {
                int base = ic*320 + (2*yo)*20 + 2*xo;
                float p[9];
                p[0]=lin[base+0];  p[1]=lin[base+1];  p[2]=lin[base+2];
                p[3]=lin[base+20]; p[4]=lin[base+21]; p[5]=lin[base+22];
                p[6]=lin[base+40]; p[7]=lin[base+41]; p[8]=lin[base+42];
#pragma unroll
                for (int k = 0; k < 9; ++k) {
                    const float4 wa  = *(const float4*)&lwT[(ic*9 + k)*32 + g*8];
                    const float4 wb4 = *(const float4*)&lwT[(ic*9 + k)*32 + g*8 + 4];
                    acc[0] += p[k]*wa.x;  acc[1] += p[k]*wa.y;
                    acc[2] += p[k]*wa.z;  acc[3] += p[k]*wa.w;
                    acc[4] += p[k]*wb4.x; acc[5] += p[k]*wb4.y;
                    acc[6] += p[k]*wb4.z; acc[7] += p[k]*wb4.w;
                }
            }
        }
        __syncthreads();
    }
    if (active) {
#pragma unroll
        for (int o = 0; o < 8; ++o) {
            int oc = octile*32 + g*8 + o;
            part[ks*N_D2E + (b*128 + oc)*49 + s] = acc[o];
        }
    }
}

// ================= d3: 128->128 3x3 s2 p1, 7x7 -> 4x4 (partial over ic) =================
// grid = 16 b * 16 ksplit(8 ic); 256 thr: g=t>>4 (8-oc group, 16 groups = 128 oc), s=t&15
__launch_bounds__(256)
__global__ void conv_d3_part(const float* __restrict__ d2, const float* __restrict__ w3,
                             float* __restrict__ part) {
    __shared__ float lin3[8*108];    // [ic][(iy+1)*12 + (ix+1)], 9 rows x 12 cols
    __shared__ float lwT3[72*128];   // [(ic*9+tap)][oc(128)]  36 KB
    int tid = threadIdx.x;
    int ks = blockIdx.x & 15;
    int b = blockIdx.x >> 4;
    int g = tid >> 4, s = tid & 15;
    int yo = s >> 2, xo = s & 3;

    // stage input: 864 floats
    for (int r = 0; r < 4; ++r) {
        int u = tid + r*256;
        if (u < 864) {
            int ic = u / 108, rem = u % 108;
            int ty = rem / 12, tx = rem % 12;
            int iy = ty - 1, ix = tx - 1;
            float v = 0.f;
            if (iy >= 0 && iy < 7 && ix >= 0 && ix < 7)
                v = d2[(b*128 + ks*8 + ic)*49 + iy*7 + ix];
            lin3[u] = v;
        }
    }
    // stage weights: 9216 floats = 36*256
#pragma unroll
    for (int r = 0; r < 36; ++r) {
        int u = tid + r*256;
        int oc_l = u / 72, rem = u % 72;
        lwT3[rem*128 + oc_l] = w3[oc_l*1152 + ks*72 + rem];
    }
    __syncthreads();

    float acc[8];
#pragma unroll
    for (int o = 0; o < 8; ++o) acc[o] = 0.f;
#pragma unroll
    for (int ic = 0; ic < 8; ++ic) {
        int base = ic*108 + (2*yo)*12 + 2*xo;
        float p[9];
        p[0]=lin3[base+0];  p[1]=lin3[base+1];  p[2]=lin3[base+2];
        p[3]=lin3[base+12]; p[4]=lin3[base+13]; p[5]=lin3[base+14];
        p[6]=lin3[base+24]; p[7]=lin3[base+25]; p[8]=lin3[base+26];
#pragma unroll
        for (int k = 0; k < 9; ++k) {
            const float4 wa  = *(const float4*)&lwT3[(ic*9 + k)*128 + g*8];
            const float4 wb4 = *(const float4*)&lwT3[(ic*9 + k)*128 + g*8 + 4];
            acc[0] += p[k]*wa.x;  acc[1] += p[k]*wa.y;
            acc[2] += p[k]*wa.z;  acc[3] += p[k]*wa.w;
            acc[4] += p[k]*wb4.x; acc[5] += p[k]*wb4.y;
            acc[6] += p[k]*wb4.z; acc[7] += p[k]*wb4.w;
        }
    }
#pragma unroll
    for (int o = 0; o < 8; ++o) {
        int oc = g*8 + o;
        part[ks*N_D3E + (b*128 + oc)*16 + s] = acc[o];
    }
}

// generic partial-sum + bias + relu; oc = (idx/SP) & 127
__global__ void reduce_relu(const float* __restrict__ part, const float* __restrict__ bias,
                            float* __restrict__ out, int nsplit, int N, int SP) {
    int idx = blockIdx.x*256 + threadIdx.x;
    if (idx >= N) return;
    int oc = (idx / SP) & 127;
    float s = 0.f;
    for (int p = 0; p < nsplit; ++p) s += part[p*N + idx];
    out[idx] = fmaxf(s + bias[oc], 0.f);
}

// ---------------- tidy 1x1 convs -> concatenated score vector ----------------
__global__ void tidy_kernel(const float* __restrict__ d1, const float* __restrict__ d2, const float* __restrict__ d3,
                            const float* __restrict__ t1w, const float* __restrict__ t1b,
                            const float* __restrict__ t2w, const float* __restrict__ t2b,
                            const float* __restrict__ t3w, const float* __restrict__ t3b,
                            float* __restrict__ scores) {
    int idx = blockIdx.x * 256 + threadIdx.x;
    if (idx >= 16*NANCH) return;
    int b = idx / NANCH, i = idx % NANCH;
    const float* src; const float* tw; const float* tb; int S, c, s;
    if (i < A1)      { c = i/196;           s = i%196;        src = d1 + b*128*196 + s; S = 196; tw = t1w; tb = t1b; }
    else if (i < A2) { int j = i - A1; c = j/49; s = j%49;    src = d2 + b*128*49  + s; S = 49;  tw = t2w; tb = t2b; }
    else             { int j = i - A2; c = j/16; s = j%16;    src = d3 + b*128*16  + s; S = 16;  tw = t3w; tb = t3b; }
    float acc = tb[c];
    const float* wr = tw + c*128;
    for (int ic = 0; ic < 128; ++ic) acc += src[ic*S] * wr[ic];
    scores[idx] = acc;
}

// ---------------- hard NMS (one block per batch) ----------------
__launch_bounds__(256)
__global__ void nms_kernel(const float* __restrict__ scores, const int* __restrict__ anc,
                           int* __restrict__ topidx, float* __restrict__ out) {
    __shared__ float s[NANCH];
    __shared__ float by0[NANCH], bx0[NANCH], by1[NANCH], bx1[NANCH], ar[NANCH];
    __shared__ float rv[256]; __shared__ int ri[256];
    __shared__ int sel[4];
    int b = blockIdx.x, tid = threadIdx.x;
    for (int j = tid; j < NANCH; j += 256) {
        s[j] = scores[b*NANCH + j];
        float y0 = (float)anc[j*4+0], x0 = (float)anc[j*4+1];
        float y1 = (float)anc[j*4+2], x1 = (float)anc[j*4+3];
        by0[j] = y0; bx0[j] = x0; by1[j] = y1; bx1[j] = x1;
        ar[j] = (y1 - y0) * (x1 - x0);
    }
    __syncthreads();
    for (int k = 0; k < 4; ++k) {
        float bv = -INFINITY; int bi = NANCH;
        for (int j = tid; j < NANCH; j += 256) {
            float v = s[j];
            if (v > bv) { bv = v; bi = j; }
        }
        rv[tid] = bv; ri[tid] = bi;
        __syncthreads();
        for (int off = 128; off > 0; off >>= 1) {
            if (tid < off) {
                float v2 = rv[tid+off]; int i2 = ri[tid+off];
                if (v2 > rv[tid] || (v2 == rv[tid] && i2 < ri[tid])) { rv[tid] = v2; ri[tid] = i2; }
            }
            __syncthreads();
        }
        int i = ri[0];
        if (tid == 0) sel[k] = i;
        float a0 = by0[i], a1 = bx0[i], a2 = by1[i], a3 = bx1[i], ai = ar[i];
        for (int j = tid; j < NANCH; j += 256) {
            float yy0 = fmaxf(by0[j], a0), xx0 = fmaxf(bx0[j], a1);
            float yy1 = fminf(by1[j], a2), xx1 = fminf(bx1[j], a3);
            float inter = fmaxf(yy1 - yy0, 0.f) * fmaxf(xx1 - xx0, 0.f);
            float iou = inter / (ar[j] + ai - inter);
            if (!(iou < 0.25f)) s[j] = -INFINITY;
        }
        if (tid == 0) s[i] = -INFINITY;
        __syncthreads();
    }
    if (tid < 4) {
        int i = sel[tid];
        topidx[b*4 + tid] = i;
        out[OUT_TIDX  + b*4 + tid] = (float)i;
        out[OUT_TPROB + b*4 + tid] = scores[b*NANCH + i];
    }
}

// ---------------- bilinear sampler: only the 49x49 pixels the 7x7/s32 conv reads ----------------
__device__ __forceinline__ float fetchpix(const float* img, int Y, int X) {
    if (Y >= 224 && Y < 672 && X >= 224 && X < 672) return img[(Y - 224)*448 + (X - 224)];
    return 0.f;
}

__global__ void sampler_kernel(const float* __restrict__ x, const int* __restrict__ anc,
                               const int* __restrict__ topidx, float* __restrict__ P) {
    int crop = blockIdx.x >> 2;
    int b = crop >> 2;
    int idx = topidx[crop];
    float y0 = (float)anc[idx*4+0], x0 = (float)anc[idx*4+1];
    float y1 = (float)anc[idx*4+2], x1 = (float)anc[idx*4+3];
    float dy = y1 - y0 - 1.0f, dx = x1 - x0 - 1.0f;
    const float* imgb = x + b*3*448*448;
    for (int u = (blockIdx.x & 3)*256 + threadIdx.x; u < 7203; u += 1024) {
        int c = u / 2401; int rem = u % 2401;
        int rid = rem / 49, cid = rem % 49;
        int oy = rid/7, ky = rid%7, ox = cid/7, kx = cid%7;
        int rr = 32*oy - 3 + ky, cc = 32*ox - 3 + kx;
        float val = 0.f;
        if (rr >= 0 && cc >= 0) {
            float ty = (float)rr / 223.0f;
            float ys = __fadd_rn(y0, __fmul_rn(ty, dy));
            int yi0 = (int)floorf(ys); yi0 = yi0 < 0 ? 0 : (yi0 > 895 ? 895 : yi0);
            int yi1 = (yi0 + 1 > 895) ? 895 : yi0 + 1;
            float wy = ys - (float)yi0;
            float tx = (float)cc / 223.0f;
            float xs = __fadd_rn(x0, __fmul_rn(tx, dx));
            int xi0 = (int)floorf(xs); xi0 = xi0 < 0 ? 0 : (xi0 > 895 ? 895 : xi0);
            int xi1 = (xi0 + 1 > 895) ? 895 : xi0 + 1;
            float wx = xs - (float)xi0;
            const float* img = imgb + c*448*448;
            float p00 = fetchpix(img, yi0, xi0), p10 = fetchpix(img, yi1, xi0);
            float p01 = fetchpix(img, yi0, xi1), p11 = fetchpix(img, yi1, xi1);
            float r0 = p00 + (p10 - p00)*wy;
            float r1 = p01 + (p11 - p01)*wy;
            val = r0 + (r1 - r0)*wx;
        }
        int pos = oy*7 + ox, kk = c*49 + ky*7 + kx;
        P[crop*7203 + pos*147 + kk] = val;
    }
}

// ---------------- feat conv as GEMM (K=147) fused with relu+mean ----------------
__launch_bounds__(256)
__global__ void feat_gemm_kernel(const float* __restrict__ P, const float* __restrict__ fw,
                                 const float* __restrict__ fb, float* __restrict__ pf) {
    __shared__ float lp[49*148];
    int crop = blockIdx.x >> 3, tile = blockIdx.x & 7;
    int oc = tile*256 + threadIdx.x;
    for (int u = threadIdx.x; u < 7203; u += 256)
        lp[(u/147)*148 + (u%147)] = P[crop*7203 + u];
    __syncthreads();
    float s[49];
#pragma unroll
    for (int p = 0; p < 49; ++p) s[p] = 0.f;
    const float* wr = fw + oc*147;
    for (int kc = 0; kc < 36; ++kc) {
        float w0 = wr[kc*4], w1 = wr[kc*4+1], w2 = wr[kc*4+2], w3 = wr[kc*4+3];
#pragma unroll
        for (int p = 0; p < 49; ++p) {
            float4 v = *(const float4*)&lp[p*148 + kc*4];
            s[p] += v.x*w0 + v.y*w1 + v.z*w2 + v.w*w3;
        }
    }
    {
        float w0 = wr[144], w1 = wr[145], w2 = wr[146];
#pragma unroll
        for (int p = 0; p < 49; ++p)
            s[p] += lp[p*148+144]*w0 + lp[p*148+145]*w1 + lp[p*148+146]*w2;
    }
    float bias = fb[oc], acc = 0.f;
#pragma unroll
    for (int p = 0; p < 49; ++p) acc += fmaxf(s[p] + bias, 0.f);
    pf[crop*2048 + oc] = acc / 49.0f;
}

// ---------------- part logits ----------------
__global__ void partcls_kernel(const float* __restrict__ pf, const float* __restrict__ pw,
                               const float* __restrict__ pb, float* __restrict__ out) {
    int o = blockIdx.x; int crop = o / 200, cls = o % 200;
    int lane = threadIdx.x;
    const float* a = pf + crop*2048; const float* w = pw + cls*2048;
    float sum = 0.f;
#pragma unroll
    for (int i = 0; i < 8; ++i) {
        int k = lane*4 + i*256;
        float4 a4 = *(const float4*)&a[k];
        float4 w4 = *(const float4*)&w[k];
        sum += a4.x*w4.x + a4.y*w4.y + a4.z*w4.z + a4.w*w4.w;
    }
#pragma unroll
    for (int off = 32; off > 0; off >>= 1) sum += __shfl_down(sum, off);
    if (lane == 0) out[OUT_PART + o] = sum + pb[cls];
}

// ---------------- concat logits: one block per class, 16 batches per block ----------------
__launch_bounds__(256)
__global__ void concat_kernel(const float* __restrict__ pf, const float* __restrict__ feature,
                              const float* __restrict__ cw, const float* __restrict__ cb,
                              float* __restrict__ out) {
    __shared__ float red[4][16];
    int j = blockIdx.x, tid = threadIdx.x;
    const float* w = cw + (size_t)j*10240;
    float acc[16];
#pragma unroll
    for (int b = 0; b < 16; ++b) acc[b] = 0.f;
    for (int k = tid; k < 10240; k += 256) {
        float wk = w[k];
        const float* v; int stride;
        if (k < 8192) { v = pf + k; stride = 8192; }
        else          { v = feature + (k - 8192); stride = 2048; }
#pragma unroll
        for (int b = 0; b < 16; ++b) acc[b] += v[b*stride] * wk;
    }
#pragma unroll
    for (int b = 0; b < 16; ++b) {
        float s2 = acc[b];
#pragma unroll
        for (int off = 32; off > 0; off >>= 1) s2 += __shfl_down(s2, off);
        if ((tid & 63) == 0) red[tid >> 6][b] = s2;
    }
    __syncthreads();
    if (tid < 16)
        out[OUT_CONCAT + tid*200 + j] = red[0][tid] + red[1][tid] + red[2][tid] + red[3][tid] + cb[j];
}

extern "C" void kernel_launch(void* const* d_in, const int* in_sizes, int n_in,
                              void* d_out, int out_size, void* d_ws, size_t ws_size,
                              hipStream_t stream) {
    const float* x    = (const float*)d_in[0];
    const float* rpn  = (const float*)d_in[1];
    const float* feat = (const float*)d_in[2];
    const float* rout = (const float*)d_in[3];
    const float* d1w  = (const float*)d_in[4];
    const float* d1b  = (const float*)d_in[5];
    const float* d2w  = (const float*)d_in[6];
    const float* d2b  = (const float*)d_in[7];
    const float* d3w  = (const float*)d_in[8];
    const float* d3b  = (const float*)d_in[9];
    const float* t1w  = (const float*)d_in[10];
    const float* t1b  = (const float*)d_in[11];
    const float* t2w  = (const float*)d_in[12];
    const float* t2b  = (const float*)d_in[13];
    const float* t3w  = (const float*)d_in[14];
    const float* t3b  = (const float*)d_in[15];
    const float* fw   = (const float*)d_in[16];
    const float* fbb  = (const float*)d_in[17];
    const float* pw   = (const float*)d_in[18];
    const float* pb   = (const float*)d_in[19];
    const float* cw   = (const float*)d_in[20];
    const float* cb   = (const float*)d_in[21];
    float* out = (float*)d_out;
    float* wsf = (float*)d_ws;
    float* d1  = wsf + OFF_D1;
    float* d2  = wsf + OFF_D2;
    float* d3  = wsf + OFF_D3;
    float* sc  = wsf + OFF_SC;
    float* pfb = wsf + OFF_PF;
    float* P   = wsf + OFF_P;
    int* anc    = (int*)(wsf + OFF_INT);
    int* topidx = anc + NANCH*4;

    // resnet_out passthrough
    hipMemcpyAsync(out, rout, 3200*sizeof(float), hipMemcpyDeviceToDevice, stream);

    anchor_kernel<<<7, 256, 0, stream>>>(anc);

    bool use_mfma = ws_size >= (size_t)TOTAL_MFMA_F * sizeof(float);
    if (use_mfma) {
        unsigned short* ath = (unsigned short*)(wsf + OFF_ATH);
        unsigned short* atl = (unsigned short*)(wsf + OFF_ATL);
        unsigned short* bwh = (unsigned short*)(wsf + OFF_BWH);
        unsigned short* bwl = (unsigned short*)(wsf + OFF_BWL);
        float* pm = wsf + OFF_PM;
        split_rpn_t<<<1024, 256, 0, stream>>>(rpn, ath, atl);
        split_w<<<9216, 256, 0, stream>>>(d1w, bwh, bwl);
        d1_mfma<<<98*9, 256, 0, stream>>>(ath, atl, bwh, bwl, pm);
        d1_combine<<<(3136*128 + 255)/256, 256, 0, stream>>>(pm, d1b, d1);
    } else {
        float* part = wsf + OFF_BIG;
        conv_d1_part<<<16*16*KSPLIT, 256, 0, stream>>>(rpn, d1w, part);
        d1_reduce<<<(N_D1E + 255)/256, 256, 0, stream>>>(part, d1b, d1);
    }

    // d2/d3 partials reuse the (now dead) d1-staging region
    float* part2 = wsf + OFF_P2;
    float* part3 = wsf + OFF_P3;
    conv_d2_part<<<256, 256, 0, stream>>>(d1, d2w, part2);
    reduce_relu<<<(N_D2E + 255)/256, 256, 0, stream>>>(part2, d2b, d2, 4, N_D2E, 49);
    conv_d3_part<<<256, 256, 0, stream>>>(d2, d3w, part3);
    reduce_relu<<<(N_D3E + 255)/256, 256, 0, stream>>>(part3, d3b, d3, 16, N_D3E, 16);

    tidy_kernel<<<101, 256, 0, stream>>>(d1, d2, d3, t1w, t1b, t2w, t2b, t3w, t3b, sc);
    nms_kernel<<<16, 256, 0, stream>>>(sc, anc, topidx, out);
    sampler_kernel<<<256, 256, 0, stream>>>(x, anc, topidx, P);
    feat_gemm_kernel<<<512, 256, 0, stream>>>(P, fw, fbb, pfb);
    partcls_kernel<<<12800, 64, 0, stream>>>(pfb, pw, pb, out);
    concat_kernel<<<200, 256, 0, stream>>>(pfb, feat, cw, cb, out);
}

// Round 6
// 391.428 us; speedup vs baseline: 1.7383x; 1.0537x over previous
//
#include <hip/hip_runtime.h>
#include <math.h>

#define NANCH 1614
#define A1 1176
#define A2 1470
#define KSPLIT 4
#define N_D1E (16*128*196)   // 401408 elements of d1

// ---------------- workspace layout (float offsets) ----------------
#define OFF_D1 0
#define OFF_D2 401408
#define OFF_D3 501760
#define OFF_SC 534528
#define OFF_PF 560352
#define OFF_P  691424
#define OFF_INT 1152416          // ints: anchors 1614*4, topidx 64 (6528 slots)
#define OFF_BIG 1158944          // union region, 16B aligned
// MFMA-path union members (float offsets from OFF_BIG):
#define SZ_AT 3211264            // 16*196*2048 ushort = this many floats
#define SZ_BW 1179648            // 9*128*2048 ushort  = this many floats
#define OFF_ATH (OFF_BIG)
#define OFF_ATL (OFF_ATH + SZ_AT)
#define OFF_BWH (OFF_ATL + SZ_AT)
#define OFF_BWL (OFF_BWH + SZ_BW)
#define OFF_PM  (OFF_BWL + SZ_BW)
#define SZ_PM   3612672          // 9*3136*128 floats
#define TOTAL_MFMA_F (OFF_PM + SZ_PM)          // 13,553,440 floats = 54.2 MB
// After d1 is finalized, the OFF_BIG region is dead -> reuse for d2/d3 partials.
#define N_D2E (16*128*49)        // 100352
#define N_D3E (16*128*16)        // 32768
#define OFF_P2 OFF_BIG
#define OFF_P3 (OFF_BIG + 4*N_D2E)

// output layout (floats): resnet_out[3200] | concat_logits[3200] | part_logits[12800] | top_idx[64] | top_n_prob[64]
#define OUT_CONCAT 3200
#define OUT_PART   6400
#define OUT_TIDX   19200
#define OUT_TPROB  19264

typedef __attribute__((ext_vector_type(8))) short short8;
typedef __attribute__((ext_vector_type(4))) float f32x4;

__device__ __forceinline__ unsigned short bf16_rn(float f) {
    unsigned u = __float_as_uint(f);
    unsigned r = u + 0x7fffu + ((u >> 16) & 1u);   // RN-even
    return (unsigned short)(r >> 16);
}
__device__ __forceinline__ float bf16_to_f(unsigned short h) {
    return __uint_as_float(((unsigned)h) << 16);
}

// ---------------- anchors (replicates _gen_edge_anchors in f64) ----------------
__global__ void anchor_kernel(int* __restrict__ anc) {
    int i = blockIdx.x * 256 + threadIdx.x;
    if (i >= NANCH) return;
    int stride, n, sgroup, j;
    double size;
    if (i < A1)      { stride = 32;  size = 48.0;  n = 14; j = i;      sgroup = 0; }
    else if (i < A2) { stride = 64;  size = 96.0;  n = 7;  j = i - A1; sgroup = 0; }
    else             { stride = 128; size = 192.0; n = 4;  j = i - A2; sgroup = 1; }
    int cells = n * n;
    int combo = j / cells, cell = j % cells;
    int sc_i = combo / 3, ar_i = combo % 3;
    double sc;
    if (sgroup == 0) sc = pow(2.0, (double)(sc_i + 1) / 3.0);
    else             sc = (sc_i == 0) ? 1.0 : pow(2.0, (double)sc_i / 3.0);
    double ar = (ar_i == 0) ? 0.667 : ((ar_i == 1) ? 1.0 : 1.5);
    int y = cell / n, x = cell % n;
    double cy = (double)y * stride + stride / 2.0;
    double cx = (double)x * stride + stride / 2.0;
    double sq = sqrt(ar);
    double h = size * sc / sq, w = size * sc * sq;
    anc[i*4+0] = (int)(cy - h/2.0 + 224.0);
    anc[i*4+1] = (int)(cx - w/2.0 + 224.0);
    anc[i*4+2] = (int)(cy + h/2.0 + 224.0);
    anc[i*4+3] = (int)(cx + w/2.0 + 224.0);
}

// ================= MFMA d1 path =================
// T row stride 197 (odd): transpose-read phase hits 32 distinct banks
__launch_bounds__(256)
__global__ void split_rpn_t(const float* __restrict__ rpn,
                            unsigned short* __restrict__ ath, unsigned short* __restrict__ atl) {
    __shared__ float T[32*197];
    int b = blockIdx.x >> 6, icb = blockIdx.x & 63;   // 64 ic-blocks of 32
    int tid = threadIdx.x;
    for (int idx = tid; idx < 32*196; idx += 256) {
        int i = idx / 196, s = idx % 196;
        T[i*197 + s] = rpn[((size_t)(b*2048 + icb*32 + i))*196 + s];
    }
    __syncthreads();
    for (int idx = tid; idx < 32*196; idx += 256) {
        int s = idx >> 5, i = idx & 31;
        float f = T[i*197 + s];
        unsigned short hi = bf16_rn(f);
        unsigned short lo = bf16_rn(f - bf16_to_f(hi));
        size_t o = ((size_t)(b*196 + s))*2048 + icb*32 + i;
        ath[o] = hi; atl[o] = lo;
    }
}

__global__ void split_w(const float* __restrict__ w1,
                        unsigned short* __restrict__ bwh, unsigned short* __restrict__ bwl) {
    int idx = blockIdx.x * 256 + threadIdx.x;
    if (idx >= 9*128*2048) return;
    int tap = idx / (128*2048);
    int rem = idx % (128*2048);
    int oc = rem >> 11, ic = rem & 2047;
    float f = w1[((size_t)(oc*2048 + ic))*9 + tap];
    unsigned short hi = bf16_rn(f);
    unsigned short lo = bf16_rn(f - bf16_to_f(hi));
    bwh[idx] = hi; bwl[idx] = lo;
}

// GEMM: partM[tap][row=(b,s)][oc] = sum_ic A[row][tap,ic] * B[tap,ic][oc]
// 441 blocks = 9 taps x 49 mb(64 rows). 4 waves, wave-tile 32x64.
// Double-buffered LDS, ONE barrier/step; per step/wave: 12 ds_read_b128, 24 MFMA.
#define ABUF (64*40)    // shorts per A buffer (pad 32->40)
#define BBUF (128*40)   // shorts per B buffer
__launch_bounds__(256)
__global__ void d1_mfma(const unsigned short* __restrict__ ath, const unsigned short* __restrict__ atl,
                        const unsigned short* __restrict__ bwh, const unsigned short* __restrict__ bwl,
                        float* __restrict__ partM) {
    __shared__ unsigned short Ah[2*ABUF], Al[2*ABUF], Bh[2*BBUF], Bl[2*BBUF]; // 61440 B
    int tid = threadIdx.x;
    int tap = blockIdx.x / 49, mb = blockIdx.x % 49;
    int dy = tap/3 - 1, dx = tap%3 - 1;
    int wave = tid >> 6, lane = tid & 63;
    int wr = wave >> 1, wc = wave & 1;
    int lg = lane >> 4, lr = lane & 15;

    // A staging (2 reps): idx in [0,512): row=idx>>3, half=(idx>>2)&1, slot=idx&3
    const unsigned short* asrc[2]; unsigned short* adst[2]; bool avalid[2];
#pragma unroll
    for (int rep = 0; rep < 2; ++rep) {
        int idx = rep*256 + tid;
        int rw = idx >> 3, half = (idx >> 2) & 1, slot = idx & 3;
        int grow = mb*64 + rw;
        int b = grow / 196, s = grow % 196;
        int y = s / 14, x = s % 14;
        int ys = y + dy, xs = x + dx;
        bool av = (ys >= 0) && (ys < 14) && (xs >= 0) && (xs < 14);
        avalid[rep] = av;
        asrc[rep] = (half ? atl : ath)
            + ((size_t)(b*196 + (av ? (ys*14 + xs) : 0)))*2048 + slot*8;
        adst[rep] = (half ? Al : Ah) + rw*40 + slot*8;
    }
    // B staging (4 reps): idx in [0,1024): oc=idx>>3, half=(idx>>2)&1, slot=idx&3
    const unsigned short* bsrc[4]; unsigned short* bdst[4];
#pragma unroll
    for (int rep = 0; rep < 4; ++rep) {
        int idx = rep*256 + tid;
        int oc = idx >> 3, half = (idx >> 2) & 1, slot = idx & 3;
        bsrc[rep] = (half ? bwl : bwh) + ((size_t)(tap*128 + oc))*2048 + slot*8;
        bdst[rep] = (half ? Bl : Bh) + oc*40 + slot*8;
    }

    f32x4 acc[2][4];
#pragma unroll
    for (int r2 = 0; r2 < 2; ++r2)
#pragma unroll
        for (int f = 0; f < 4; ++f) acc[r2][f] = (f32x4){0.f, 0.f, 0.f, 0.f};
    const short8 zer = {0,0,0,0,0,0,0,0};

    short8 ga[2], gb[4];
    // prologue: fetch + write buffer 0
#pragma unroll
    for (int rep = 0; rep < 2; ++rep) ga[rep] = avalid[rep] ? *(const short8*)(asrc[rep]) : zer;
#pragma unroll
    for (int rep = 0; rep < 4; ++rep) gb[rep] = *(const short8*)(bsrc[rep]);
#pragma unroll
    for (int rep = 0; rep < 2; ++rep) *(short8*)(adst[rep]) = ga[rep];
#pragma unroll
    for (int rep = 0; rep < 4; ++rep) *(short8*)(bdst[rep]) = gb[rep];
    __syncthreads();

    int abase_w = wr*32*40 + lr*40 + lg*8;   // lane's A-frag offset (row wr*32+lr), +16*40 for r2=1
    int bbase_w = wc*64*40 + lg*8;           // + f*16*40 + lr*40

    for (int step = 0; step < 64; ++step) {
        int buf = step & 1;
        // issue next-step global loads early (hide under MFMA phase)
        if (step + 1 < 64) {
            int ic0 = (step + 1) * 32;
#pragma unroll
            for (int rep = 0; rep < 2; ++rep) ga[rep] = avalid[rep] ? *(const short8*)(asrc[rep] + ic0) : zer;
#pragma unroll
            for (int rep = 0; rep < 4; ++rep) gb[rep] = *(const short8*)(bsrc[rep] + ic0);
        }
        int ab = buf*ABUF, bb = buf*BBUF;
        short8 ah0 = *(const short8*)&Ah[ab + abase_w];
        short8 ah1 = *(const short8*)&Ah[ab + abase_w + 16*40];
        short8 al0 = *(const short8*)&Al[ab + abase_w];
        short8 al1 = *(const short8*)&Al[ab + abase_w + 16*40];
#pragma unroll
        for (int f = 0; f < 4; ++f) {
            int bo = bb + bbase_w + (f*16 + lr)*40;
            short8 b_h = *(const short8*)&Bh[bo];
            short8 b_l = *(const short8*)&Bl[bo];
            // 3-pass split-bf16 (order preserved: hh, hl, lh)
            acc[0][f] = __builtin_amdgcn_mfma_f32_16x16x32_bf16(ah0, b_h, acc[0][f], 0, 0, 0);
            acc[0][f] = __builtin_amdgcn_mfma_f32_16x16x32_bf16(ah0, b_l, acc[0][f], 0, 0, 0);
            acc[0][f] = __builtin_amdgcn_mfma_f32_16x16x32_bf16(al0, b_h, acc[0][f], 0, 0, 0);
            acc[1][f] = __builtin_amdgcn_mfma_f32_16x16x32_bf16(ah1, b_h, acc[1][f], 0, 0, 0);
            acc[1][f] = __builtin_amdgcn_mfma_f32_16x16x32_bf16(ah1, b_l, acc[1][f], 0, 0, 0);
            acc[1][f] = __builtin_amdgcn_mfma_f32_16x16x32_bf16(al1, b_h, acc[1][f], 0, 0, 0);
        }
        // write next buffer (vmcnt wait lands here, after MFMA phase)
        if (step + 1 < 64) {
            int nb = buf ^ 1;
#pragma unroll
            for (int rep = 0; rep < 2; ++rep) *(short8*)(adst[rep] + nb*ABUF) = ga[rep];
#pragma unroll
            for (int rep = 0; rep < 4; ++rep) *(short8*)(bdst[rep] + nb*BBUF) = gb[rep];
        }
        __syncthreads();
    }
    // C/D layout (m89-verified): col = lane&15, row = (lane>>4)*4 + reg
#pragma unroll
    for (int r2 = 0; r2 < 2; ++r2)
#pragma unroll
    for (int f = 0; f < 4; ++f) {
        int oc = wc*64 + f*16 + lr;
#pragma unroll
        for (int r = 0; r < 4; ++r) {
            int row = mb*64 + wr*32 + r2*16 + lg*4 + r;
            partM[((size_t)tap*3136 + row)*128 + oc] = acc[r2][f][r];
        }
    }
}

__global__ void d1_combine(const float* __restrict__ partM, const float* __restrict__ b1,
                           float* __restrict__ d1) {
    int idx = blockIdx.x*256 + threadIdx.x;
    if (idx >= 3136*128) return;
    int oc = idx & 127, row = idx >> 7;
    float s = 0.f;
#pragma unroll
    for (int t = 0; t < 9; ++t) s += partM[(size_t)t*3136*128 + idx];
    int b = row / 196, sp = row % 196;
    d1[(b*128 + oc)*196 + sp] = fmaxf(s + b1[oc], 0.f);
}

// ================= fp32 fallback d1 path (used if ws_size too small) =================
__launch_bounds__(256)
__global__ void conv_d1_part(const float* __restrict__ rpn, const float* __restrict__ w1,
                             float* __restrict__ part) {
    __shared__ float lin[8*256];
    __shared__ float lwT[576];
    int tid = threadIdx.x;
    int ks = blockIdx.x & 3;
    int tile = (blockIdx.x >> 2) & 15;
    int b = blockIdx.x >> 6;
    int py = tid >> 4, px = tid & 15;
    bool pvalid = (py >= 1) && (py <= 14) && (px >= 1) && (px <= 14);
    int in_off = (b*2048)*196 + (py-1)*14 + (px-1);
    const float* wb = w1 + tile*8*18432;
    int s = tid, y = s / 14, x = s % 14;
    bool active = s < 196;
    float acc[8];
#pragma unroll
    for (int o = 0; o < 8; ++o) acc[o] = 0.f;
    float pv[8]; float wv[3];
    int c0 = ks * 64;
#pragma unroll
    for (int i = 0; i < 8; ++i) pv[i] = pvalid ? rpn[in_off + (c0*8 + i)*196] : 0.f;
#pragma unroll
    for (int r = 0; r < 3; ++r) {
        int u = tid + r*256;
        if (u < 576) { int oc = u/72, rem = u%72; wv[r] = wb[oc*18432 + c0*72 + rem]; }
    }
    for (int c = 0; c < 64; ++c) {
#pragma unroll
        for (int i = 0; i < 8; ++i) lin[i*256 + tid] = pv[i];
#pragma unroll
        for (int r = 0; r < 3; ++r) {
            int u = tid + r*256;
            if (u < 576) { int oc = u/72, rem = u%72; lwT[rem*8 + oc] = wv[r]; }
        }
        __syncthreads();
        if (c + 1 < 64) {
            int icb = (c0 + c + 1) * 8;
#pragma unroll
            for (int i = 0; i < 8; ++i) pv[i] = pvalid ? rpn[in_off + (icb + i)*196] : 0.f;
#pragma unroll
            for (int r = 0; r < 3; ++r) {
                int u = tid + r*256;
                if (u < 576) { int oc = u/72, rem = u%72; wv[r] = wb[oc*18432 + icb*9 + rem]; }
            }
        }
        if (active) {
#pragma unroll
            for (int ic = 0; ic < 8; ++ic) {
                int base = ic*256 + y*16 + x;
                float p[9];
                p[0]=lin[base+0];  p[1]=lin[base+1];  p[2]=lin[base+2];
                p[3]=lin[base+16]; p[4]=lin[base+17]; p[5]=lin[base+18];
                p[6]=lin[base+32]; p[7]=lin[base+33]; p[8]=lin[base+34];
#pragma unroll
                for (int k = 0; k < 9; ++k) {
                    const float4 wa  = *(const float4*)&lwT[(ic*9 + k)*8];
                    const float4 wb4 = *(const float4*)&lwT[(ic*9 + k)*8 + 4];
                    acc[0] += p[k]*wa.x;  acc[1] += p[k]*wa.y;
                    acc[2] += p[k]*wa.z;  acc[3] += p[k]*wa.w;
                    acc[4] += p[k]*wb4.x; acc[5] += p[k]*wb4.y;
                    acc[6] += p[k]*wb4.z; acc[7] += p[k]*wb4.w;
                }
            }
        }
        __syncthreads();
    }
    if (active) {
#pragma unroll
        for (int o = 0; o < 8; ++o) {
            int oc = tile*8 + o;
            part[ks*N_D1E + (b*128 + oc)*196 + s] = acc[o];
        }
    }
}

__global__ void d1_reduce(const float* __restrict__ part, const float* __restrict__ b1,
                          float* __restrict__ d1) {
    int idx = blockIdx.x * 256 + threadIdx.x;
    if (idx >= N_D1E) return;
    int oc = (idx / 196) & 127;
    float s = part[idx] + part[idx + N_D1E] + part[idx + 2*N_D1E] + part[idx + 3*N_D1E];
    d1[idx] = fmaxf(s + b1[oc], 0.f);
}

// ================= d2: 128->128 3x3 s2 p1, 14x14 -> 7x7 (partial over ic) =================
__launch_bounds__(256)
__global__ void conv_d2_part(const float* __restrict__ d1, const float* __restrict__ w2,
                             float* __restrict__ part) {
    __shared__ float lin[8*320];    // [ic][py*20+px], stride 20 breaks 32-float bank alias
    __shared__ float lwT[72*32];    // [(ic*9+tap)][oc_l(32)]
    int tid = threadIdx.x;
    int ks = blockIdx.x & 3;
    int octile = (blockIdx.x >> 2) & 3;
    int b = blockIdx.x >> 4;
    int py = tid >> 4, px = tid & 15;
    bool pvalid = (py >= 1) && (py <= 14) && (px >= 1) && (px <= 14);
    int in_base = (b*128)*196 + (py-1)*14 + (px-1);
    int g = tid >> 6, s = tid & 63;
    int yo = s / 7, xo = s % 7;
    bool active = s < 49;
    const float* wb = w2 + (octile*32)*1152 + ks*288;

    float acc[8];
#pragma unroll
    for (int o = 0; o < 8; ++o) acc[o] = 0.f;
    float pv[8], wv[9];
#pragma unroll
    for (int i = 0; i < 8; ++i) pv[i] = pvalid ? d1[in_base + (ks*32 + i)*196] : 0.f;
#pragma unroll
    for (int r = 0; r < 9; ++r) {
        int u = tid + r*256; int oc_l = u/72, rem = u%72;
        wv[r] = wb[oc_l*1152 + rem];
    }
    for (int c = 0; c < 4; ++c) {
#pragma unroll
        for (int i = 0; i < 8; ++i) lin[i*320 + py*20 + px] = pv[i];
#pragma unroll
        for (int r = 0; r < 9; ++r) {
            int u = tid + r*256; int oc_l = u/72, rem = u%72;
            lwT[rem*32 + oc_l] = wv[r];
        }
        __syncthreads();
        if (c + 1 < 4) {
            int ic0 = ks*32 + (c+1)*8;
#pragma unroll
            for (int i = 0; i < 8; ++i) pv[i] = pvalid ? d1[in_base + (ic0 + i)*196] : 0.f;
#pragma unroll
            for (int r = 0; r < 9; ++r) {
                int u = tid + r*256; int oc_l = u/72, rem = u%72;
                wv[r] = wb[oc_l*1152 + (c+1)*72 + rem];
            }
        }
        if (active) {
#pragma unroll
            for (int ic = 0; ic < 8; ++ic) {
                int base = ic*320 + (2*yo)*20 + 2*xo;
                float p[9];
                p[0]=lin[base+0];  p[1]=lin[base+1];  p[2]=lin[base+2];
                p[3]=lin[base+20]; p[4]=lin[base+21]; p[5]=lin[base+22];
                p[6]=lin[base+40]; p[7]=lin[base+41]; p[8]=lin[base+42];
#pragma unroll
                for (int k = 0; k < 9; ++k) {
                    const float4 wa  = *(const float4*)&lwT[(ic*9 + k)*32 + g*8];
                    const float4 wb4 = *(const float4*)&lwT[(ic*9 + k)*32 + g*8 + 4];
                    acc[0] += p[k]*wa.x;  acc[1] += p[k]*wa.y;
                    acc[2] += p[k]*wa.z;  acc[3] += p[k]*wa.w;
                    acc[4] += p[k]*wb4.x; acc[5] += p[k]*wb4.y;
                    acc[6] += p[k]*wb4.z; acc[7] += p[k]*wb4.w;
                }
            }
        }
        __syncthreads();
    }
    if (active) {
#pragma unroll
        for (int o = 0; o < 8; ++o) {
            int oc = octile*32 + g*8 + o;
            part[ks*N_D2E + (b*128 + oc)*49 + s] = acc[o];
        }
    }
}

// ================= d3: 128->128 3x3 s2 p1, 7x7 -> 4x4 (partial over ic) =================
__launch_bounds__(256)
__global__ void conv_d3_part(const float* __restrict__ d2, const float* __restrict__ w3,
                             float* __restrict__ part) {
    __shared__ float lin3[8*108];
    __shared__ float lwT3[72*128];
    int tid = threadIdx.x;
    int ks = blockIdx.x & 15;
    int b = blockIdx.x >> 4;
    int g = tid >> 4, s = tid & 15;
    int yo = s >> 2, xo = s & 3;

    for (int r = 0; r < 4; ++r) {
        int u = tid + r*256;
        if (u < 864) {
            int ic = u / 108, rem = u % 108;
            int ty = rem / 12, tx = rem % 12;
            int iy = ty - 1, ix = tx - 1;
            float v = 0.f;
            if (iy >= 0 && iy < 7 && ix >= 0 && ix < 7)
                v = d2[(b*128 + ks*8 + ic)*49 + iy*7 + ix];
            lin3[u] = v;
        }
    }
#pragma unroll
    for (int r = 0; r < 36; ++r) {
        int u = tid + r*256;
        int oc_l = u / 72, rem = u % 72;
        lwT3[rem*128 + oc_l] = w3[oc_l*1152 + ks*72 + rem];
    }
    __syncthreads();

    float acc[8];
#pragma unroll
    for (int o = 0; o < 8; ++o) acc[o] = 0.f;
#pragma unroll
    for (int ic = 0; ic < 8; ++ic) {
        int base = ic*108 + (2*yo)*12 + 2*xo;
        float p[9];
        p[0]=lin3[base+0];  p[1]=lin3[base+1];  p[2]=lin3[base+2];
        p[3]=lin3[base+12]; p[4]=lin3[base+13]; p[5]=lin3[base+14];
        p[6]=lin3[base+24]; p[7]=lin3[base+25]; p[8]=lin3[base+26];
#pragma unroll
        for (int k = 0; k < 9; ++k) {
            const float4 wa  = *(const float4*)&lwT3[(ic*9 + k)*128 + g*8];
            const float4 wb4 = *(const float4*)&lwT3[(ic*9 + k)*128 + g*8 + 4];
            acc[0] += p[k]*wa.x;  acc[1] += p[k]*wa.y;
            acc[2] += p[k]*wa.z;  acc[3] += p[k]*wa.w;
            acc[4] += p[k]*wb4.x; acc[5] += p[k]*wb4.y;
            acc[6] += p[k]*wb4.z; acc[7] += p[k]*wb4.w;
        }
    }
#pragma unroll
    for (int o = 0; o < 8; ++o) {
        int oc = g*8 + o;
        part[ks*N_D3E + (b*128 + oc)*16 + s] = acc[o];
    }
}

__global__ void reduce_relu(const float* __restrict__ part, const float* __restrict__ bias,
                            float* __restrict__ out, int nsplit, int N, int SP) {
    int idx = blockIdx.x*256 + threadIdx.x;
    if (idx >= N) return;
    int oc = (idx / SP) & 127;
    float s = 0.f;
    for (int p = 0; p < nsplit; ++p) s += part[p*N + idx];
    out[idx] = fmaxf(s + bias[oc], 0.f);
}

// ---------------- tidy 1x1 convs -> concatenated score vector ----------------
__global__ void tidy_kernel(const float* __restrict__ d1, const float* __restrict__ d2, const float* __restrict__ d3,
                            const float* __restrict__ t1w, const float* __restrict__ t1b,
                            const float* __restrict__ t2w, const float* __restrict__ t2b,
                            const float* __restrict__ t3w, const float* __restrict__ t3b,
                            float* __restrict__ scores) {
    int idx = blockIdx.x * 256 + threadIdx.x;
    if (idx >= 16*NANCH) return;
    int b = idx / NANCH, i = idx % NANCH;
    const float* src; const float* tw; const float* tb; int S, c, s;
    if (i < A1)      { c = i/196;           s = i%196;        src = d1 + b*128*196 + s; S = 196; tw = t1w; tb = t1b; }
    else if (i < A2) { int j = i - A1; c = j/49; s = j%49;    src = d2 + b*128*49  + s; S = 49;  tw = t2w; tb = t2b; }
    else             { int j = i - A2; c = j/16; s = j%16;    src = d3 + b*128*16  + s; S = 16;  tw = t3w; tb = t3b; }
    float acc = tb[c];
    const float* wr = tw + c*128;
    for (int ic = 0; ic < 128; ++ic) acc += src[ic*S] * wr[ic];
    scores[idx] = acc;
}

// ---------------- hard NMS (one block per batch) ----------------
__launch_bounds__(256)
__global__ void nms_kernel(const float* __restrict__ scores, const int* __restrict__ anc,
                           int* __restrict__ topidx, float* __restrict__ out) {
    __shared__ float s[NANCH];
    __shared__ float by0[NANCH], bx0[NANCH], by1[NANCH], bx1[NANCH], ar[NANCH];
    __shared__ float rv[256]; __shared__ int ri[256];
    __shared__ int sel[4];
    int b = blockIdx.x, tid = threadIdx.x;
    for (int j = tid; j < NANCH; j += 256) {
        s[j] = scores[b*NANCH + j];
        float y0 = (float)anc[j*4+0], x0 = (float)anc[j*4+1];
        float y1 = (float)anc[j*4+2], x1 = (float)anc[j*4+3];
        by0[j] = y0; bx0[j] = x0; by1[j] = y1; bx1[j] = x1;
        ar[j] = (y1 - y0) * (x1 - x0);
    }
    __syncthreads();
    for (int k = 0; k < 4; ++k) {
        float bv = -INFINITY; int bi = NANCH;
        for (int j = tid; j < NANCH; j += 256) {
            float v = s[j];
            if (v > bv) { bv = v; bi = j; }
        }
        rv[tid] = bv; ri[tid] = bi;
        __syncthreads();
        for (int off = 128; off > 0; off >>= 1) {
            if (tid < off) {
                float v2 = rv[tid+off]; int i2 = ri[tid+off];
                if (v2 > rv[tid] || (v2 == rv[tid] && i2 < ri[tid])) { rv[tid] = v2; ri[tid] = i2; }
            }
            __syncthreads();
        }
        int i = ri[0];
        if (tid == 0) sel[k] = i;
        float a0 = by0[i], a1 = bx0[i], a2 = by1[i], a3 = bx1[i], ai = ar[i];
        for (int j = tid; j < NANCH; j += 256) {
            float yy0 = fmaxf(by0[j], a0), xx0 = fmaxf(bx0[j], a1);
            float yy1 = fminf(by1[j], a2), xx1 = fminf(bx1[j], a3);
            float inter = fmaxf(yy1 - yy0, 0.f) * fmaxf(xx1 - xx0, 0.f);
            float iou = inter / (ar[j] + ai - inter);
            if (!(iou < 0.25f)) s[j] = -INFINITY;
        }
        if (tid == 0) s[i] = -INFINITY;
        __syncthreads();
    }
    if (tid < 4) {
        int i = sel[tid];
        topidx[b*4 + tid] = i;
        out[OUT_TIDX  + b*4 + tid] = (float)i;
        out[OUT_TPROB + b*4 + tid] = scores[b*NANCH + i];
    }
}

// ---------------- bilinear sampler: only the 49x49 pixels the 7x7/s32 conv reads ----------------
__device__ __forceinline__ float fetchpix(const float* img, int Y, int X) {
    if (Y >= 224 && Y < 672 && X >= 224 && X < 672) return img[(Y - 224)*448 + (X - 224)];
    return 0.f;
}

__global__ void sampler_kernel(const float* __restrict__ x, const int* __restrict__ anc,
                               const int* __restrict__ topidx, float* __restrict__ P) {
    int crop = blockIdx.x >> 2;
    int b = crop >> 2;
    int idx = topidx[crop];
    float y0 = (float)anc[idx*4+0], x0 = (float)anc[idx*4+1];
    float y1 = (float)anc[idx*4+2], x1 = (float)anc[idx*4+3];
    float dy = y1 - y0 - 1.0f, dx = x1 - x0 - 1.0f;
    const float* imgb = x + b*3*448*448;
    for (int u = (blockIdx.x & 3)*256 + threadIdx.x; u < 7203; u += 1024) {
        int c = u / 2401; int rem = u % 2401;
        int rid = rem / 49, cid = rem % 49;
        int oy = rid/7, ky = rid%7, ox = cid/7, kx = cid%7;
        int rr = 32*oy - 3 + ky, cc = 32*ox - 3 + kx;
        float val = 0.f;
        if (rr >= 0 && cc >= 0) {
            float ty = (float)rr / 223.0f;
            float ys = __fadd_rn(y0, __fmul_rn(ty, dy));
            int yi0 = (int)floorf(ys); yi0 = yi0 < 0 ? 0 : (yi0 > 895 ? 895 : yi0);
            int yi1 = (yi0 + 1 > 895) ? 895 : yi0 + 1;
            float wy = ys - (float)yi0;
            float tx = (float)cc / 223.0f;
            float xs = __fadd_rn(x0, __fmul_rn(tx, dx));
            int xi0 = (int)floorf(xs); xi0 = xi0 < 0 ? 0 : (xi0 > 895 ? 895 : xi0);
            int xi1 = (xi0 + 1 > 895) ? 895 : xi0 + 1;
            float wx = xs - (float)xi0;
            const float* img = imgb + c*448*448;
            float p00 = fetchpix(img, yi0, xi0), p10 = fetchpix(img, yi1, xi0);
            float p01 = fetchpix(img, yi0, xi1), p11 = fetchpix(img, yi1, xi1);
            float r0 = p00 + (p10 - p00)*wy;
            float r1 = p01 + (p11 - p01)*wy;
            val = r0 + (r1 - r0)*wx;
        }
        int pos = oy*7 + ox, kk = c*49 + ky*7 + kx;
        P[crop*7203 + pos*147 + kk] = val;
    }
}

// ---------------- feat conv as GEMM (K=147) fused with relu+mean ----------------
__launch_bounds__(256)
__global__ void feat_gemm_kernel(const float* __restrict__ P, const float* __restrict__ fw,
                                 const float* __restrict__ fb, float* __restrict__ pf) {
    __shared__ float lp[49*148];
    int crop = blockIdx.x >> 3, tile = blockIdx.x & 7;
    int oc = tile*256 + threadIdx.x;
    for (int u = threadIdx.x; u < 7203; u += 256)
        lp[(u/147)*148 + (u%147)] = P[crop*7203 + u];
    __syncthreads();
    float s[49];
#pragma unroll
    for (int p = 0; p < 49; ++p) s[p] = 0.f;
    const float* wr = fw + oc*147;
    for (int kc = 0; kc < 36; ++kc) {
        float w0 = wr[kc*4], w1 = wr[kc*4+1], w2 = wr[kc*4+2], w3 = wr[kc*4+3];
#pragma unroll
        for (int p = 0; p < 49; ++p) {
            float4 v = *(const float4*)&lp[p*148 + kc*4];
            s[p] += v.x*w0 + v.y*w1 + v.z*w2 + v.w*w3;
        }
    }
    {
        float w0 = wr[144], w1 = wr[145], w2 = wr[146];
#pragma unroll
        for (int p = 0; p < 49; ++p)
            s[p] += lp[p*148+144]*w0 + lp[p*148+145]*w1 + lp[p*148+146]*w2;
    }
    float bias = fb[oc], acc = 0.f;
#pragma unroll
    for (int p = 0; p < 49; ++p) acc += fmaxf(s[p] + bias, 0.f);
    pf[crop*2048 + oc] = acc / 49.0f;
}

// ---------------- part logits ----------------
__global__ void partcls_kernel(const float* __restrict__ pf, const float* __restrict__ pw,
                               const float* __restrict__ pb, float* __restrict__ out) {
    int o = blockIdx.x; int crop = o / 200, cls = o % 200;
    int lane = threadIdx.x;
    const float* a = pf + crop*2048; const float* w = pw + cls*2048;
    float sum = 0.f;
#pragma unroll
    for (int i = 0; i < 8; ++i) {
        int k = lane*4 + i*256;
        float4 a4 = *(const float4*)&a[k];
        float4 w4 = *(const float4*)&w[k];
        sum += a4.x*w4.x + a4.y*w4.y + a4.z*w4.z + a4.w*w4.w;
    }
#pragma unroll
    for (int off = 32; off > 0; off >>= 1) sum += __shfl_down(sum, off);
    if (lane == 0) out[OUT_PART + o] = sum + pb[cls];
}

// ---------------- concat logits: one block per class, 16 batches per block ----------------
__launch_bounds__(256)
__global__ void concat_kernel(const float* __restrict__ pf, const float* __restrict__ feature,
                              const float* __restrict__ cw, const float* __restrict__ cb,
                              float* __restrict__ out) {
    __shared__ float red[4][16];
    int j = blockIdx.x, tid = threadIdx.x;
    const float* w = cw + (size_t)j*10240;
    float acc[16];
#pragma unroll
    for (int b = 0; b < 16; ++b) acc[b] = 0.f;
    for (int k = tid; k < 10240; k += 256) {
        float wk = w[k];
        const float* v; int stride;
        if (k < 8192) { v = pf + k; stride = 8192; }
        else          { v = feature + (k - 8192); stride = 2048; }
#pragma unroll
        for (int b = 0; b < 16; ++b) acc[b] += v[b*stride] * wk;
    }
#pragma unroll
    for (int b = 0; b < 16; ++b) {
        float s2 = acc[b];
#pragma unroll
        for (int off = 32; off > 0; off >>= 1) s2 += __shfl_down(s2, off);
        if ((tid & 63) == 0) red[tid >> 6][b] = s2;
    }
    __syncthreads();
    if (tid < 16)
        out[OUT_CONCAT + tid*200 + j] = red[0][tid] + red[1][tid] + red[2][tid] + red[3][tid] + cb[j];
}

extern "C" void kernel_launch(void* const* d_in, const int* in_sizes, int n_in,
                              void* d_out, int out_size, void* d_ws, size_t ws_size,
                              hipStream_t stream) {
    const float* x    = (const float*)d_in[0];
    const float* rpn  = (const float*)d_in[1];
    const float* feat = (const float*)d_in[2];
    const float* rout = (const float*)d_in[3];
    const float* d1w  = (const float*)d_in[4];
    const float* d1b  = (const float*)d_in[5];
    const float* d2w  = (const float*)d_in[6];
    const float* d2b  = (const float*)d_in[7];
    const float* d3w  = (const float*)d_in[8];
    const float* d3b  = (const float*)d_in[9];
    const float* t1w  = (const float*)d_in[10];
    const float* t1b  = (const float*)d_in[11];
    const float* t2w  = (const float*)d_in[12];
    const float* t2b  = (const float*)d_in[13];
    const float* t3w  = (const float*)d_in[14];
    const float* t3b  = (const float*)d_in[15];
    const float* fw   = (const float*)d_in[16];
    const float* fbb  = (const float*)d_in[17];
    const float* pw   = (const float*)d_in[18];
    const float* pb   = (const float*)d_in[19];
    const float* cw   = (const float*)d_in[20];
    const float* cb   = (const float*)d_in[21];
    float* out = (float*)d_out;
    float* wsf = (float*)d_ws;
    float* d1  = wsf + OFF_D1;
    float* d2  = wsf + OFF_D2;
    float* d3  = wsf + OFF_D3;
    float* sc  = wsf + OFF_SC;
    float* pfb = wsf + OFF_PF;
    float* P   = wsf + OFF_P;
    int* anc    = (int*)(wsf + OFF_INT);
    int* topidx = anc + NANCH*4;

    // resnet_out passthrough
    hipMemcpyAsync(out, rout, 3200*sizeof(float), hipMemcpyDeviceToDevice, stream);

    anchor_kernel<<<7, 256, 0, stream>>>(anc);

    bool use_mfma = ws_size >= (size_t)TOTAL_MFMA_F * sizeof(float);
    if (use_mfma) {
        unsigned short* ath = (unsigned short*)(wsf + OFF_ATH);
        unsigned short* atl = (unsigned short*)(wsf + OFF_ATL);
        unsigned short* bwh = (unsigned short*)(wsf + OFF_BWH);
        unsigned short* bwl = (unsigned short*)(wsf + OFF_BWL);
        float* pm = wsf + OFF_PM;
        split_rpn_t<<<1024, 256, 0, stream>>>(rpn, ath, atl);
        split_w<<<9216, 256, 0, stream>>>(d1w, bwh, bwl);
        d1_mfma<<<441, 256, 0, stream>>>(ath, atl, bwh, bwl, pm);
        d1_combine<<<(3136*128 + 255)/256, 256, 0, stream>>>(pm, d1b, d1);
    } else {
        float* part = wsf + OFF_BIG;
        conv_d1_part<<<16*16*KSPLIT, 256, 0, stream>>>(rpn, d1w, part);
        d1_reduce<<<(N_D1E + 255)/256, 256, 0, stream>>>(part, d1b, d1);
    }

    // d2/d3 partials reuse the (now dead) d1-staging region
    float* part2 = wsf + OFF_P2;
    float* part3 = wsf + OFF_P3;
    conv_d2_part<<<256, 256, 0, stream>>>(d1, d2w, part2);
    reduce_relu<<<(N_D2E + 255)/256, 256, 0, stream>>>(part2, d2b, d2, 4, N_D2E, 49);
    conv_d3_part<<<256, 256, 0, stream>>>(d2, d3w, part3);
    reduce_relu<<<(N_D3E + 255)/256, 256, 0, stream>>>(part3, d3b, d3, 16, N_D3E, 16);

    tidy_kernel<<<101, 256, 0, stream>>>(d1, d2, d3, t1w, t1b, t2w, t2b, t3w, t3b, sc);
    nms_kernel<<<16, 256, 0, stream>>>(sc, anc, topidx, out);
    sampler_kernel<<<256, 256, 0, stream>>>(x, anc, topidx, P);
    feat_gemm_kernel<<<512, 256, 0, stream>>>(P, fw, fbb, pfb);
    partcls_kernel<<<12800, 64, 0, stream>>>(pfb, pw, pb, out);
    concat_kernel<<<200, 256, 0, stream>>>(pfb, feat, cw, cb, out);
}

// Round 10
// 336.611 us; speedup vs baseline: 2.0214x; 1.1629x over previous
//
#include <hip/hip_runtime.h>
#include <math.h>

#define NANCH 1614
#define A1 1176
#define A2 1470
#define KSPLIT 4
#define N_D1E (16*128*196)   // 401408 elements of d1

// ---------------- workspace layout (float offsets) ----------------
#define OFF_D1 0
#define OFF_D2 401408
#define OFF_D3 501760
#define OFF_SC 534528
#define OFF_PF 560352
#define OFF_P  691424
#define OFF_INT 1152416          // ints: anchors 1614*4, topidx 64 (6528 slots)
#define OFF_BIG 1158944          // union region, 16B aligned
// MFMA-path union members (float offsets from OFF_BIG):
#define SZ_AT 3211264            // 16*196*2048 ushort = this many floats
#define SZ_BW 1179648            // 9*128*2048 ushort  = this many floats
#define OFF_ATH (OFF_BIG)
#define OFF_ATL (OFF_ATH + SZ_AT)
#define OFF_BWH (OFF_ATL + SZ_AT)
#define OFF_BWL (OFF_BWH + SZ_BW)
#define OFF_PM  (OFF_BWL + SZ_BW)
#define SZ_PM   3612672          // 9*3136*128 floats
#define TOTAL_MFMA_F (OFF_PM + SZ_PM)          // 54.2 MB
// After d1_combine, the PM region is dead -> reuse for feat MFMA operands:
#define OFF_BFH OFF_PM                   // Bfh: 2048*160 ushort = 163840 float-slots
#define OFF_BFL (OFF_PM + 163840)
#define OFF_PH  (OFF_PM + 327680)        // Ph: 64*49*160 ushort = 250880 float-slots
#define OFF_PL  (OFF_PM + 327680 + 250880)
// After d1 is finalized, the OFF_BIG..OFF_PM staging is dead -> d2/d3 partials.
#define N_D2E (16*128*49)        // 100352
#define N_D3E (16*128*16)        // 32768
#define OFF_P2 OFF_BIG
#define OFF_P3 (OFF_BIG + 4*N_D2E)

// output layout (floats): resnet_out[3200] | concat_logits[3200] | part_logits[12800] | top_idx[64] | top_n_prob[64]
#define OUT_CONCAT 3200
#define OUT_PART   6400
#define OUT_TIDX   19200
#define OUT_TPROB  19264

typedef __attribute__((ext_vector_type(8))) short short8;
typedef __attribute__((ext_vector_type(4))) float f32x4;

__device__ __forceinline__ unsigned short bf16_rn(float f) {
    unsigned u = __float_as_uint(f);
    unsigned r = u + 0x7fffu + ((u >> 16) & 1u);   // RN-even
    return (unsigned short)(r >> 16);
}
__device__ __forceinline__ float bf16_to_f(unsigned short h) {
    return __uint_as_float(((unsigned)h) << 16);
}

// ---------------- anchors (replicates _gen_edge_anchors in f64) ----------------
__global__ void anchor_kernel(int* __restrict__ anc) {
    int i = blockIdx.x * 256 + threadIdx.x;
    if (i >= NANCH) return;
    int stride, n, sgroup, j;
    double size;
    if (i < A1)      { stride = 32;  size = 48.0;  n = 14; j = i;      sgroup = 0; }
    else if (i < A2) { stride = 64;  size = 96.0;  n = 7;  j = i - A1; sgroup = 0; }
    else             { stride = 128; size = 192.0; n = 4;  j = i - A2; sgroup = 1; }
    int cells = n * n;
    int combo = j / cells, cell = j % cells;
    int sc_i = combo / 3, ar_i = combo % 3;
    double sc;
    if (sgroup == 0) sc = pow(2.0, (double)(sc_i + 1) / 3.0);
    else             sc = (sc_i == 0) ? 1.0 : pow(2.0, (double)sc_i / 3.0);
    double ar = (ar_i == 0) ? 0.667 : ((ar_i == 1) ? 1.0 : 1.5);
    int y = cell / n, x = cell % n;
    double cy = (double)y * stride + stride / 2.0;
    double cx = (double)x * stride + stride / 2.0;
    double sq = sqrt(ar);
    double h = size * sc / sq, w = size * sc * sq;
    anc[i*4+0] = (int)(cy - h/2.0 + 224.0);
    anc[i*4+1] = (int)(cx - w/2.0 + 224.0);
    anc[i*4+2] = (int)(cy + h/2.0 + 224.0);
    anc[i*4+3] = (int)(cx + w/2.0 + 224.0);
}

// ================= MFMA d1 path =================
__launch_bounds__(256)
__global__ void split_rpn_t(const float* __restrict__ rpn,
                            unsigned short* __restrict__ ath, unsigned short* __restrict__ atl) {
    __shared__ float T[32*197];
    int b = blockIdx.x >> 6, icb = blockIdx.x & 63;
    int tid = threadIdx.x;
    for (int idx = tid; idx < 32*196; idx += 256) {
        int i = idx / 196, s = idx % 196;
        T[i*197 + s] = rpn[((size_t)(b*2048 + icb*32 + i))*196 + s];
    }
    __syncthreads();
    for (int idx = tid; idx < 32*196; idx += 256) {
        int s = idx >> 5, i = idx & 31;
        float f = T[i*197 + s];
        unsigned short hi = bf16_rn(f);
        unsigned short lo = bf16_rn(f - bf16_to_f(hi));
        size_t o = ((size_t)(b*196 + s))*2048 + icb*32 + i;
        ath[o] = hi; atl[o] = lo;
    }
}

__global__ void split_w(const float* __restrict__ w1,
                        unsigned short* __restrict__ bwh, unsigned short* __restrict__ bwl) {
    int idx = blockIdx.x * 256 + threadIdx.x;
    if (idx >= 9*128*2048) return;
    int tap = idx / (128*2048);
    int rem = idx % (128*2048);
    int oc = rem >> 11, ic = rem & 2047;
    float f = w1[((size_t)(oc*2048 + ic))*9 + tap];
    unsigned short hi = bf16_rn(f);
    unsigned short lo = bf16_rn(f - bf16_to_f(hi));
    bwh[idx] = hi; bwl[idx] = lo;
}

// GEMM: partM[tap][row=(b,s)][oc] = sum_ic A[row][tap,ic] * B[tap,ic][oc]
// 504 blocks (63 idle), XCD-swizzled so all taps of one mb share an XCD and
// same-tap blocks are adjacent. Stride-32 LDS + XOR k-slot swizzle -> 48 KB, 3 blocks/CU.
#define ABUF 2048    // 64*32 shorts per buffer
#define BBUF 4096    // 128*32
__launch_bounds__(256)
__global__ void d1_mfma(const unsigned short* __restrict__ ath, const unsigned short* __restrict__ atl,
                        const unsigned short* __restrict__ bwh, const unsigned short* __restrict__ bwl,
                        float* __restrict__ partM) {
    __shared__ unsigned short Ah[2*ABUF], Al[2*ABUF], Bh[2*BBUF], Bl[2*BBUF]; // 49152 B
    int tid = threadIdx.x;
    // swizzled decode: bid = (tap*7 + mb/8)*8 + (mb&7)
    int q = blockIdx.x >> 3;
    int tap = q / 7, g = q % 7;
    int mb = g*8 + (blockIdx.x & 7);
    if (mb >= 49) return;                 // 63 idle blocks
    int dy = tap/3 - 1, dx = tap%3 - 1;
    int wave = tid >> 6, lane = tid & 63;
    int wr = wave >> 1, wc = wave & 1;
    int lg = lane >> 4, lr = lane & 15;
    int ksw = (lg ^ (lr & 3)) << 3;       // XOR k-slot swizzle (shorts)

    const unsigned short* asrc[2]; unsigned short* adst[2]; bool avalid[2];
#pragma unroll
    for (int rep = 0; rep < 2; ++rep) {
        int idx = rep*256 + tid;
        int rw = idx >> 3, half = (idx >> 2) & 1, slot = idx & 3;
        int grow = mb*64 + rw;
        int b = grow / 196, s = grow % 196;
        int y = s / 14, x = s % 14;
        int ys = y + dy, xs = x + dx;
        bool av = (ys >= 0) && (ys < 14) && (xs >= 0) && (xs < 14);
        avalid[rep] = av;
        asrc[rep] = (half ? atl : ath)
            + ((size_t)(b*196 + (av ? (ys*14 + xs) : 0)))*2048 + slot*8;
        adst[rep] = (half ? Al : Ah) + rw*32 + ((slot ^ (rw & 3)) << 3);
    }
    const unsigned short* bsrc[4]; unsigned short* bdst[4];
#pragma unroll
    for (int rep = 0; rep < 4; ++rep) {
        int idx = rep*256 + tid;
        int oc = idx >> 3, half = (idx >> 2) & 1, slot = idx & 3;
        bsrc[rep] = (half ? bwl : bwh) + ((size_t)(tap*128 + oc))*2048 + slot*8;
        bdst[rep] = (half ? Bl : Bh) + oc*32 + ((slot ^ (oc & 3)) << 3);
    }

    f32x4 acc[2][4];
#pragma unroll
    for (int r2 = 0; r2 < 2; ++r2)
#pragma unroll
        for (int f = 0; f < 4; ++f) acc[r2][f] = (f32x4){0.f, 0.f, 0.f, 0.f};
    const short8 zer = {0,0,0,0,0,0,0,0};

    short8 ga[2], gb[4];
#pragma unroll
    for (int rep = 0; rep < 2; ++rep) ga[rep] = avalid[rep] ? *(const short8*)(asrc[rep]) : zer;
#pragma unroll
    for (int rep = 0; rep < 4; ++rep) gb[rep] = *(const short8*)(bsrc[rep]);
#pragma unroll
    for (int rep = 0; rep < 2; ++rep) *(short8*)(adst[rep]) = ga[rep];
#pragma unroll
    for (int rep = 0; rep < 4; ++rep) *(short8*)(bdst[rep]) = gb[rep];
    __syncthreads();

    int arow0 = (wr*32 + lr)*32 + ksw;         // r2=0 row; +16*32 for r2=1
    int bbase = (wc*64 + lr)*32 + ksw;         // + f*16*32

    for (int step = 0; step < 64; ++step) {
        int buf = step & 1;
        if (step + 1 < 64) {
            int ic0 = (step + 1) * 32;
#pragma unroll
            for (int rep = 0; rep < 2; ++rep) ga[rep] = avalid[rep] ? *(const short8*)(asrc[rep] + ic0) : zer;
#pragma unroll
            for (int rep = 0; rep < 4; ++rep) gb[rep] = *(const short8*)(bsrc[rep] + ic0);
        }
        int ab = buf*ABUF, bb = buf*BBUF;
        short8 ah0 = *(const short8*)&Ah[ab + arow0];
        short8 ah1 = *(const short8*)&Ah[ab + arow0 + 16*32];
        short8 al0 = *(const short8*)&Al[ab + arow0];
        short8 al1 = *(const short8*)&Al[ab + arow0 + 16*32];
#pragma unroll
        for (int f = 0; f < 4; ++f) {
            int bo = bb + bbase + f*16*32;
            short8 b_h = *(const short8*)&Bh[bo];
            short8 b_l = *(const short8*)&Bl[bo];
            acc[0][f] = __builtin_amdgcn_mfma_f32_16x16x32_bf16(ah0, b_h, acc[0][f], 0, 0, 0);
            acc[0][f] = __builtin_amdgcn_mfma_f32_16x16x32_bf16(ah0, b_l, acc[0][f], 0, 0, 0);
            acc[0][f] = __builtin_amdgcn_mfma_f32_16x16x32_bf16(al0, b_h, acc[0][f], 0, 0, 0);
            acc[1][f] = __builtin_amdgcn_mfma_f32_16x16x32_bf16(ah1, b_h, acc[1][f], 0, 0, 0);
            acc[1][f] = __builtin_amdgcn_mfma_f32_16x16x32_bf16(ah1, b_l, acc[1][f], 0, 0, 0);
            acc[1][f] = __builtin_amdgcn_mfma_f32_16x16x32_bf16(al1, b_h, acc[1][f], 0, 0, 0);
        }
        if (step + 1 < 64) {
            int nb = buf ^ 1;
#pragma unroll
            for (int rep = 0; rep < 2; ++rep) *(short8*)(adst[rep] + nb*ABUF) = ga[rep];
#pragma unroll
            for (int rep = 0; rep < 4; ++rep) *(short8*)(bdst[rep] + nb*BBUF) = gb[rep];
        }
        __syncthreads();
    }
#pragma unroll
    for (int r2 = 0; r2 < 2; ++r2)
#pragma unroll
    for (int f = 0; f < 4; ++f) {
        int oc = wc*64 + f*16 + lr;
#pragma unroll
        for (int r = 0; r < 4; ++r) {
            int row = mb*64 + wr*32 + r2*16 + lg*4 + r;
            partM[((size_t)tap*3136 + row)*128 + oc] = acc[r2][f][r];
        }
    }
}

__global__ void d1_combine(const float* __restrict__ partM, const float* __restrict__ b1,
                           float* __restrict__ d1) {
    int idx = blockIdx.x*256 + threadIdx.x;
    if (idx >= 3136*128) return;
    int oc = idx & 127, row = idx >> 7;
    float s = 0.f;
#pragma unroll
    for (int t = 0; t < 9; ++t) s += partM[(size_t)t*3136*128 + idx];
    int b = row / 196, sp = row % 196;
    d1[(b*128 + oc)*196 + sp] = fmaxf(s + b1[oc], 0.f);
}

// ================= fp32 fallback d1 path (used if ws_size too small) =================
__launch_bounds__(256)
__global__ void conv_d1_part(const float* __restrict__ rpn, const float* __restrict__ w1,
                             float* __restrict__ part) {
    __shared__ float lin[8*256];
    __shared__ float lwT[576];
    int tid = threadIdx.x;
    int ks = blockIdx.x & 3;
    int tile = (blockIdx.x >> 2) & 15;
    int b = blockIdx.x >> 6;
    int py = tid >> 4, px = tid & 15;
    bool pvalid = (py >= 1) && (py <= 14) && (px >= 1) && (px <= 14);
    int in_off = (b*2048)*196 + (py-1)*14 + (px-1);
    const float* wb = w1 + tile*8*18432;
    int s = tid, y = s / 14, x = s % 14;
    bool active = s < 196;
    float acc[8];
#pragma unroll
    for (int o = 0; o < 8; ++o) acc[o] = 0.f;
    float pv[8]; float wv[3];
    int c0 = ks * 64;
#pragma unroll
    for (int i = 0; i < 8; ++i) pv[i] = pvalid ? rpn[in_off + (c0*8 + i)*196] : 0.f;
#pragma unroll
    for (int r = 0; r < 3; ++r) {
        int u = tid + r*256;
        if (u < 576) { int oc = u/72, rem = u%72; wv[r] = wb[oc*18432 + c0*72 + rem]; }
    }
    for (int c = 0; c < 64; ++c) {
#pragma unroll
        for (int i = 0; i < 8; ++i) lin[i*256 + tid] = pv[i];
#pragma unroll
        for (int r = 0; r < 3; ++r) {
            int u = tid + r*256;
            if (u < 576) { int oc = u/72, rem = u%72; lwT[rem*8 + oc] = wv[r]; }
        }
        __syncthreads();
        if (c + 1 < 64) {
            int icb = (c0 + c + 1) * 8;
#pragma unroll
            for (int i = 0; i < 8; ++i) pv[i] = pvalid ? rpn[in_off + (icb + i)*196] : 0.f;
#pragma unroll
            for (int r = 0; r < 3; ++r) {
                int u = tid + r*256;
                if (u < 576) { int oc = u/72, rem = u%72; wv[r] = wb[oc*18432 + icb*9 + rem]; }
            }
        }
        if (active) {
#pragma unroll
            for (int ic = 0; ic < 8; ++ic) {
                int base = ic*256 + y*16 + x;
                float p[9];
                p[0]=lin[base+0];  p[1]=lin[base+1];  p[2]=lin[base+2];
                p[3]=lin[base+16]; p[4]=lin[base+17]; p[5]=lin[base+18];
                p[6]=lin[base+32]; p[7]=lin[base+33]; p[8]=lin[base+34];
#pragma unroll
                for (int k = 0; k < 9; ++k) {
                    const float4 wa  = *(const float4*)&lwT[(ic*9 + k)*8];
                    const float4 wb4 = *(const float4*)&lwT[(ic*9 + k)*8 + 4];
                    acc[0] += p[k]*wa.x;  acc[1] += p[k]*wa.y;
                    acc[2] += p[k]*wa.z;  acc[3] += p[k]*wa.w;
                    acc[4] += p[k]*wb4.x; acc[5] += p[k]*wb4.y;
                    acc[6] += p[k]*wb4.z; acc[7] += p[k]*wb4.w;
                }
            }
        }
        __syncthreads();
    }
    if (active) {
#pragma unroll
        for (int o = 0; o < 8; ++o) {
            int oc = tile*8 + o;
            part[ks*N_D1E + (b*128 + oc)*196 + s] = acc[o];
        }
    }
}

__global__ void d1_reduce(const float* __restrict__ part, const float* __restrict__ b1,
                          float* __restrict__ d1) {
    int idx = blockIdx.x * 256 + threadIdx.x;
    if (idx >= N_D1E) return;
    int oc = (idx / 196) & 127;
    float s = part[idx] + part[idx + N_D1E] + part[idx + 2*N_D1E] + part[idx + 3*N_D1E];
    d1[idx] = fmaxf(s + b1[oc], 0.f);
}

// ================= d2 / d3 =================
__launch_bounds__(256)
__global__ void conv_d2_part(const float* __restrict__ d1, const float* __restrict__ w2,
                             float* __restrict__ part) {
    __shared__ float lin[8*320];
    __shared__ float lwT[72*32];
    int tid = threadIdx.x;
    int ks = blockIdx.x & 3;
    int octile = (blockIdx.x >> 2) & 3;
    int b = blockIdx.x >> 4;
    int py = tid >> 4, px = tid & 15;
    bool pvalid = (py >= 1) && (py <= 14) && (px >= 1) && (px <= 14);
    int in_base = (b*128)*196 + (py-1)*14 + (px-1);
    int g = tid >> 6, s = tid & 63;
    int yo = s / 7, xo = s % 7;
    bool active = s < 49;
    const float* wb = w2 + (octile*32)*1152 + ks*288;

    float acc[8];
#pragma unroll
    for (int o = 0; o < 8; ++o) acc[o] = 0.f;
    float pv[8], wv[9];
#pragma unroll
    for (int i = 0; i < 8; ++i) pv[i] = pvalid ? d1[in_base + (ks*32 + i)*196] : 0.f;
#pragma unroll
    for (int r = 0; r < 9; ++r) {
        int u = tid + r*256; int oc_l = u/72, rem = u%72;
        wv[r] = wb[oc_l*1152 + rem];
    }
    for (int c = 0; c < 4; ++c) {
#pragma unroll
        for (int i = 0; i < 8; ++i) lin[i*320 + py*20 + px] = pv[i];
#pragma unroll
        for (int r = 0; r < 9; ++r) {
            int u = tid + r*256; int oc_l = u/72, rem = u%72;
            lwT[rem*32 + oc_l] = wv[r];
        }
        __syncthreads();
        if (c + 1 < 4) {
            int ic0 = ks*32 + (c+1)*8;
#pragma unroll
            for (int i = 0; i < 8; ++i) pv[i] = pvalid ? d1[in_base + (ic0 + i)*196] : 0.f;
#pragma unroll
            for (int r = 0; r < 9; ++r) {
                int u = tid + r*256; int oc_l = u/72, rem = u%72;
                wv[r] = wb[oc_l*1152 + (c+1)*72 + rem];
            }
        }
        if (active) {
#pragma unroll
            for (int ic = 0; ic < 8; ++ic) {
                int base = ic*320 + (2*yo)*20 + 2*xo;
                float p[9];
                p[0]=lin[base+0];  p[1]=lin[base+1];  p[2]=lin[base+2];
                p[3]=lin[base+20]; p[4]=lin[base+21]; p[5]=lin[base+22];
                p[6]=lin[base+40]; p[7]=lin[base+41]; p[8]=lin[base+42];
#pragma unroll
                for (int k = 0; k < 9; ++k) {
                    const float4 wa  = *(const float4*)&lwT[(ic*9 + k)*32 + g*8];
                    const float4 wb4 = *(const float4*)&lwT[(ic*9 + k)*32 + g*8 + 4];
                    acc[0] += p[k]*wa.x;  acc[1] += p[k]*wa.y;
                    acc[2] += p[k]*wa.z;  acc[3] += p[k]*wa.w;
                    acc[4] += p[k]*wb4.x; acc[5] += p[k]*wb4.y;
                    acc[6] += p[k]*wb4.z; acc[7] += p[k]*wb4.w;
                }
            }
        }
        __syncthreads();
    }
    if (active) {
#pragma unroll
        for (int o = 0; o < 8; ++o) {
            int oc = octile*32 + g*8 + o;
            part[ks*N_D2E + (b*128 + oc)*49 + s] = acc[o];
        }
    }
}

__launch_bounds__(256)
__global__ void conv_d3_part(const float* __restrict__ d2, const float* __restrict__ w3,
                             float* __restrict__ part) {
    __shared__ float lin3[8*108];
    __shared__ float lwT3[72*128];
    int tid = threadIdx.x;
    int ks = blockIdx.x & 15;
    int b = blockIdx.x >> 4;
    int g = tid >> 4, s = tid & 15;
    int yo = s >> 2, xo = s & 3;

    for (int r = 0; r < 4; ++r) {
        int u = tid + r*256;
        if (u < 864) {
            int ic = u / 108, rem = u % 108;
            int ty = rem / 12, tx = rem % 12;
            int iy = ty - 1, ix = tx - 1;
            float v = 0.f;
            if (iy >= 0 && iy < 7 && ix >= 0 && ix < 7)
                v = d2[(b*128 + ks*8 + ic)*49 + iy*7 + ix];
            lin3[u] = v;
        }
    }
#pragma unroll
    for (int r = 0; r < 36; ++r) {
        int u = tid + r*256;
        int oc_l = u / 72, rem = u % 72;
        lwT3[rem*128 + oc_l] = w3[oc_l*1152 + ks*72 + rem];
    }
    __syncthreads();

    float acc[8];
#pragma unroll
    for (int o = 0; o < 8; ++o) acc[o] = 0.f;
#pragma unroll
    for (int ic = 0; ic < 8; ++ic) {
        int base = ic*108 + (2*yo)*12 + 2*xo;
        float p[9];
        p[0]=lin3[base+0];  p[1]=lin3[base+1];  p[2]=lin3[base+2];
        p[3]=lin3[base+12]; p[4]=lin3[base+13]; p[5]=lin3[base+14];
        p[6]=lin3[base+24]; p[7]=lin3[base+25]; p[8]=lin3[base+26];
#pragma unroll
        for (int k = 0; k < 9; ++k) {
            const float4 wa  = *(const float4*)&lwT3[(ic*9 + k)*128 + g*8];
            const float4 wb4 = *(const float4*)&lwT3[(ic*9 + k)*128 + g*8 + 4];
            acc[0] += p[k]*wa.x;  acc[1] += p[k]*wa.y;
            acc[2] += p[k]*wa.z;  acc[3] += p[k]*wa.w;
            acc[4] += p[k]*wb4.x; acc[5] += p[k]*wb4.y;
            acc[6] += p[k]*wb4.z; acc[7] += p[k]*wb4.w;
        }
    }
#pragma unroll
    for (int o = 0; o < 8; ++o) {
        int oc = g*8 + o;
        part[ks*N_D3E + (b*128 + oc)*16 + s] = acc[o];
    }
}

__global__ void reduce_relu(const float* __restrict__ part, const float* __restrict__ bias,
                            float* __restrict__ out, int nsplit, int N, int SP) {
    int idx = blockIdx.x*256 + threadIdx.x;
    if (idx >= N) return;
    int oc = (idx / SP) & 127;
    float s = 0.f;
    for (int p = 0; p < nsplit; ++p) s += part[p*N + idx];
    out[idx] = fmaxf(s + bias[oc], 0.f);
}

// ---------------- tidy 1x1 convs ----------------
__global__ void tidy_kernel(const float* __restrict__ d1, const float* __restrict__ d2, const float* __restrict__ d3,
                            const float* __restrict__ t1w, const float* __restrict__ t1b,
                            const float* __restrict__ t2w, const float* __restrict__ t2b,
                            const float* __restrict__ t3w, const float* __restrict__ t3b,
                            float* __restrict__ scores) {
    int idx = blockIdx.x * 256 + threadIdx.x;
    if (idx >= 16*NANCH) return;
    int b = idx / NANCH, i = idx % NANCH;
    const float* src; const float* tw; const float* tb; int S, c, s;
    if (i < A1)      { c = i/196;           s = i%196;        src = d1 + b*128*196 + s; S = 196; tw = t1w; tb = t1b; }
    else if (i < A2) { int j = i - A1; c = j/49; s = j%49;    src = d2 + b*128*49  + s; S = 49;  tw = t2w; tb = t2b; }
    else             { int j = i - A2; c = j/16; s = j%16;    src = d3 + b*128*16  + s; S = 16;  tw = t3w; tb = t3b; }
    float acc = tb[c];
    const float* wr = tw + c*128;
    for (int ic = 0; ic < 128; ++ic) acc += src[ic*S] * wr[ic];
    scores[idx] = acc;
}

// ---------------- hard NMS ----------------
__launch_bounds__(256)
__global__ void nms_kernel(const float* __restrict__ scores, const int* __restrict__ anc,
                           int* __restrict__ topidx, float* __restrict__ out) {
    __shared__ float s[NANCH];
    __shared__ float by0[NANCH], bx0[NANCH], by1[NANCH], bx1[NANCH], ar[NANCH];
    __shared__ float rv[256]; __shared__ int ri[256];
    __shared__ int sel[4];
    int b = blockIdx.x, tid = threadIdx.x;
    for (int j = tid; j < NANCH; j += 256) {
        s[j] = scores[b*NANCH + j];
        float y0 = (float)anc[j*4+0], x0 = (float)anc[j*4+1];
        float y1 = (float)anc[j*4+2], x1 = (float)anc[j*4+3];
        by0[j] = y0; bx0[j] = x0; by1[j] = y1; bx1[j] = x1;
        ar[j] = (y1 - y0) * (x1 - x0);
    }
    __syncthreads();
    for (int k = 0; k < 4; ++k) {
        float bv = -INFINITY; int bi = NANCH;
        for (int j = tid; j < NANCH; j += 256) {
            float v = s[j];
            if (v > bv) { bv = v; bi = j; }
        }
        rv[tid] = bv; ri[tid] = bi;
        __syncthreads();
        for (int off = 128; off > 0; off >>= 1) {
            if (tid < off) {
                float v2 = rv[tid+off]; int i2 = ri[tid+off];
                if (v2 > rv[tid] || (v2 == rv[tid] && i2 < ri[tid])) { rv[tid] = v2; ri[tid] = i2; }
            }
            __syncthreads();
        }
        int i = ri[0];
        if (tid == 0) sel[k] = i;
        float a0 = by0[i], a1 = bx0[i], a2 = by1[i], a3 = bx1[i], ai = ar[i];
        for (int j = tid; j < NANCH; j += 256) {
            float yy0 = fmaxf(by0[j], a0), xx0 = fmaxf(bx0[j], a1);
            float yy1 = fminf(by1[j], a2), xx1 = fminf(bx1[j], a3);
            float inter = fmaxf(yy1 - yy0, 0.f) * fmaxf(xx1 - xx0, 0.f);
            float iou = inter / (ar[j] + ai - inter);
            if (!(iou < 0.25f)) s[j] = -INFINITY;
        }
        if (tid == 0) s[i] = -INFINITY;
        __syncthreads();
    }
    if (tid < 4) {
        int i = sel[tid];
        topidx[b*4 + tid] = i;
        out[OUT_TIDX  + b*4 + tid] = (float)i;
        out[OUT_TPROB + b*4 + tid] = scores[b*NANCH + i];
    }
}

// ---------------- bilinear samplers ----------------
__device__ __forceinline__ float fetchpix(const float* img, int Y, int X) {
    if (Y >= 224 && Y < 672 && X >= 224 && X < 672) return img[(Y - 224)*448 + (X - 224)];
    return 0.f;
}

__device__ __forceinline__ float sample_one(const float* imgb, int c, int rr, int cc,
                                            float y0, float x0, float dy, float dx) {
    float ty = (float)rr / 223.0f;
    float ys = __fadd_rn(y0, __fmul_rn(ty, dy));
    int yi0 = (int)floorf(ys); yi0 = yi0 < 0 ? 0 : (yi0 > 895 ? 895 : yi0);
    int yi1 = (yi0 + 1 > 895) ? 895 : yi0 + 1;
    float wy = ys - (float)yi0;
    float tx = (float)cc / 223.0f;
    float xs = __fadd_rn(x0, __fmul_rn(tx, dx));
    int xi0 = (int)floorf(xs); xi0 = xi0 < 0 ? 0 : (xi0 > 895 ? 895 : xi0);
    int xi1 = (xi0 + 1 > 895) ? 895 : xi0 + 1;
    float wx = xs - (float)xi0;
    const float* img = imgb + c*448*448;
    float p00 = fetchpix(img, yi0, xi0), p10 = fetchpix(img, yi1, xi0);
    float p01 = fetchpix(img, yi0, xi1), p11 = fetchpix(img, yi1, xi1);
    float r0 = p00 + (p10 - p00)*wy;
    float r1 = p01 + (p11 - p01)*wy;
    return r0 + (r1 - r0)*wx;
}

// MFMA-path sampler: writes split-bf16 Ph/Pl [crop][pos(49)][160], k>=147 zero-padded
__global__ void sampler_split_kernel(const float* __restrict__ x, const int* __restrict__ anc,
                                     const int* __restrict__ topidx,
                                     unsigned short* __restrict__ Ph, unsigned short* __restrict__ Pl) {
    int crop = blockIdx.x >> 2;
    int b = crop >> 2;
    int idx = topidx[crop];
    float y0 = (float)anc[idx*4+0], x0 = (float)anc[idx*4+1];
    float y1 = (float)anc[idx*4+2], x1 = (float)anc[idx*4+3];
    float dy = y1 - y0 - 1.0f, dx = x1 - x0 - 1.0f;
    const float* imgb = x + b*3*448*448;
    for (int u = (blockIdx.x & 3)*256 + threadIdx.x; u < 7203; u += 1024) {
        int c = u / 2401; int rem = u % 2401;
        int rid = rem / 49, cid = rem % 49;
        int oy = rid/7, ky = rid%7, ox = cid/7, kx = cid%7;
        int rr = 32*oy - 3 + ky, cc = 32*ox - 3 + kx;
        float val = 0.f;
        if (rr >= 0 && cc >= 0) val = sample_one(imgb, c, rr, cc, y0, x0, dy, dx);
        int pos = oy*7 + ox, kk = c*49 + ky*7 + kx;
        unsigned short hi = bf16_rn(val);
        unsigned short lo = bf16_rn(val - bf16_to_f(hi));
        size_t o = (size_t)crop*7840 + pos*160 + kk;
        Ph[o] = hi; Pl[o] = lo;
    }
    if ((blockIdx.x & 3) == 0) {  // zero the K pad 147..159
        for (int u = threadIdx.x; u < 49*13; u += 256) {
            int pos = u / 13, kk = 147 + u % 13;
            size_t o = (size_t)crop*7840 + pos*160 + kk;
            Ph[o] = 0; Pl[o] = 0;
        }
    }
}

// fallback sampler (fp32 P)
__global__ void sampler_kernel(const float* __restrict__ x, const int* __restrict__ anc,
                               const int* __restrict__ topidx, float* __restrict__ P) {
    int crop = blockIdx.x >> 2;
    int b = crop >> 2;
    int idx = topidx[crop];
    float y0 = (float)anc[idx*4+0], x0 = (float)anc[idx*4+1];
    float y1 = (float)anc[idx*4+2], x1 = (float)anc[idx*4+3];
    float dy = y1 - y0 - 1.0f, dx = x1 - x0 - 1.0f;
    const float* imgb = x + b*3*448*448;
    for (int u = (blockIdx.x & 3)*256 + threadIdx.x; u < 7203; u += 1024) {
        int c = u / 2401; int rem = u % 2401;
        int rid = rem / 49, cid = rem % 49;
        int oy = rid/7, ky = rid%7, ox = cid/7, kx = cid%7;
        int rr = 32*oy - 3 + ky, cc = 32*ox - 3 + kx;
        float val = 0.f;
        if (rr >= 0 && cc >= 0) val = sample_one(imgb, c, rr, cc, y0, x0, dy, dx);
        int pos = oy*7 + ox, kk = c*49 + ky*7 + kx;
        P[crop*7203 + pos*147 + kk] = val;
    }
}

// split fw -> Bfh/Bfl [oc][160]
__global__ void split_fw_kernel(const float* __restrict__ fw,
                                unsigned short* __restrict__ bfh, unsigned short* __restrict__ bfl) {
    int idx = blockIdx.x * 256 + threadIdx.x;
    if (idx >= 2048*160) return;
    int oc = idx / 160, k = idx % 160;
    float f = (k < 147) ? fw[oc*147 + k] : 0.f;
    unsigned short hi = bf16_rn(f);
    unsigned short lo = bf16_rn(f - bf16_to_f(hi));
    bfh[idx] = hi; bfl[idx] = lo;
}

// feat conv as MFMA GEMM: per block one crop x 128 oc; fused bias+relu+mean(49)
#define FAB 2048   // 64*32 shorts
#define FBB 4096   // 128*32
__launch_bounds__(256)
__global__ void feat_mfma(const unsigned short* __restrict__ Ph, const unsigned short* __restrict__ Pl,
                          const unsigned short* __restrict__ Bfh, const unsigned short* __restrict__ Bfl,
                          const float* __restrict__ fb, float* __restrict__ pf) {
    __shared__ unsigned short Ah[FAB], Al[FAB], Bh[FBB], Bl[FBB];  // 24576 B
    __shared__ float red[2][128];
    int tid = threadIdx.x;
    int crop = blockIdx.x >> 4, octile = blockIdx.x & 15;
    int wave = tid >> 6, lane = tid & 63;
    int wr = wave >> 1, wc = wave & 1;
    int lg = lane >> 4, lr = lane & 15;
    int ksw = (lg ^ (lr & 3)) << 3;

    const unsigned short* asrc[2]; unsigned short* adst[2]; bool avalid[2];
#pragma unroll
    for (int rep = 0; rep < 2; ++rep) {
        int idx = rep*256 + tid;
        int rw = idx >> 3, half = (idx >> 2) & 1, slot = idx & 3;
        bool av = rw < 49;
        avalid[rep] = av;
        int rwc = av ? rw : 0;
        asrc[rep] = (half ? Pl : Ph) + (size_t)crop*7840 + rwc*160 + slot*8;
        adst[rep] = (half ? Al : Ah) + rw*32 + ((slot ^ (rw & 3)) << 3);
    }
    const unsigned short* bsrc[4]; unsigned short* bdst[4];
#pragma unroll
    for (int rep = 0; rep < 4; ++rep) {
        int idx = rep*256 + tid;
        int oc = idx >> 3, half = (idx >> 2) & 1, slot = idx & 3;
        bsrc[rep] = (half ? Bfl : Bfh) + (size_t)(octile*128 + oc)*160 + slot*8;
        bdst[rep] = (half ? Bl : Bh) + oc*32 + ((slot ^ (oc & 3)) << 3);
    }

    f32x4 acc[2][4];
#pragma unroll
    for (int r2 = 0; r2 < 2; ++r2)
#pragma unroll
        for (int f = 0; f < 4; ++f) acc[r2][f] = (f32x4){0.f, 0.f, 0.f, 0.f};
    const short8 zer = {0,0,0,0,0,0,0,0};

    int arow0 = (wr*32 + lr)*32 + ksw;
    int bbase = (wc*64 + lr)*32 + ksw;

    for (int step = 0; step < 5; ++step) {
        int k0 = step*32;
        short8 ga[2], gb[4];
#pragma unroll
        for (int rep = 0; rep < 2; ++rep) ga[rep] = avalid[rep] ? *(const short8*)(asrc[rep] + k0) : zer;
#pragma unroll
        for (int rep = 0; rep < 4; ++rep) gb[rep] = *(const short8*)(bsrc[rep] + k0);
        __syncthreads();   // previous step's reads complete
#pragma unroll
        for (int rep = 0; rep < 2; ++rep) *(short8*)(adst[rep]) = ga[rep];
#pragma unroll
        for (int rep = 0; rep < 4; ++rep) *(short8*)(bdst[rep]) = gb[rep];
        __syncthreads();
        short8 ah0 = *(const short8*)&Ah[arow0];
        short8 ah1 = *(const short8*)&Ah[arow0 + 16*32];
        short8 al0 = *(const short8*)&Al[arow0];
        short8 al1 = *(const short8*)&Al[arow0 + 16*32];
#pragma unroll
        for (int f = 0; f < 4; ++f) {
            int bo = bbase + f*16*32;
            short8 b_h = *(const short8*)&Bh[bo];
            short8 b_l = *(const short8*)&Bl[bo];
            acc[0][f] = __builtin_amdgcn_mfma_f32_16x16x32_bf16(ah0, b_h, acc[0][f], 0, 0, 0);
            acc[0][f] = __builtin_amdgcn_mfma_f32_16x16x32_bf16(ah0, b_l, acc[0][f], 0, 0, 0);
            acc[0][f] = __builtin_amdgcn_mfma_f32_16x16x32_bf16(al0, b_h, acc[0][f], 0, 0, 0);
            acc[1][f] = __builtin_amdgcn_mfma_f32_16x16x32_bf16(ah1, b_h, acc[1][f], 0, 0, 0);
            acc[1][f] = __builtin_amdgcn_mfma_f32_16x16x32_bf16(ah1, b_l, acc[1][f], 0, 0, 0);
            acc[1][f] = __builtin_amdgcn_mfma_f32_16x16x32_bf16(al1, b_h, acc[1][f], 0, 0, 0);
        }
    }
    // epilogue: bias+relu on valid rows (<49), column sums, mean
    float colsum[4];
#pragma unroll
    for (int f = 0; f < 4; ++f) {
        float fbv = fb[octile*128 + wc*64 + f*16 + lr];
        float s = 0.f;
#pragma unroll
        for (int r2 = 0; r2 < 2; ++r2)
#pragma unroll
        for (int r = 0; r < 4; ++r) {
            int row = wr*32 + r2*16 + lg*4 + r;
            float v = fmaxf(acc[r2][f][r] + fbv, 0.f);
            if (row < 49) s += v;
        }
        s += __shfl_down(s, 32);
        s += __shfl_down(s, 16);
        colsum[f] = s;
    }
    if (lane < 16) {
#pragma unroll
        for (int f = 0; f < 4; ++f) red[wr][wc*64 + f*16 + lane] = colsum[f];
    }
    __syncthreads();
    if (tid < 128)
        pf[(size_t)crop*2048 + octile*128 + tid] = (red[0][tid] + red[1][tid]) * (1.0f/49.0f);
}

// fallback feat conv (fp32, VALU)
__launch_bounds__(256)
__global__ void feat_gemm_kernel(const float* __restrict__ P, const float* __restrict__ fw,
                                 const float* __restrict__ fb, float* __restrict__ pf) {
    __shared__ float lp[49*148];
    int crop = blockIdx.x >> 3, tile = blockIdx.x & 7;
    int oc = tile*256 + threadIdx.x;
    for (int u = threadIdx.x; u < 7203; u += 256)
        lp[(u/147)*148 + (u%147)] = P[crop*7203 + u];
    __syncthreads();
    float s[49];
#pragma unroll
    for (int p = 0; p < 49; ++p) s[p] = 0.f;
    const float* wr = fw + oc*147;
    for (int kc = 0; kc < 36; ++kc) {
        float w0 = wr[kc*4], w1 = wr[kc*4+1], w2 = wr[kc*4+2], w3 = wr[kc*4+3];
#pragma unroll
        for (int p = 0; p < 49; ++p) {
            float4 v = *(const float4*)&lp[p*148 + kc*4];
            s[p] += v.x*w0 + v.y*w1 + v.z*w2 + v.w*w3;
        }
    }
    {
        float w0 = wr[144], w1 = wr[145], w2 = wr[146];
#pragma unroll
        for (int p = 0; p < 49; ++p)
            s[p] += lp[p*148+144]*w0 + lp[p*148+145]*w1 + lp[p*148+146]*w2;
    }
    float bias = fb[oc], acc = 0.f;
#pragma unroll
    for (int p = 0; p < 49; ++p) acc += fmaxf(s[p] + bias, 0.f);
    pf[crop*2048 + oc] = acc / 49.0f;
}

// ---------------- part logits ----------------
__global__ void partcls_kernel(const float* __restrict__ pf, const float* __restrict__ pw,
                               const float* __restrict__ pb, float* __restrict__ out) {
    int o = blockIdx.x; int crop = o / 200, cls = o % 200;
    int lane = threadIdx.x;
    const float* a = pf + crop*2048; const float* w = pw + cls*2048;
    float sum = 0.f;
#pragma unroll
    for (int i = 0; i < 8; ++i) {
        int k = lane*4 + i*256;
        float4 a4 = *(const float4*)&a[k];
        float4 w4 = *(const float4*)&w[k];
        sum += a4.x*w4.x + a4.y*w4.y + a4.z*w4.z + a4.w*w4.w;
    }
#pragma unroll
    for (int off = 32; off > 0; off >>= 1) sum += __shfl_down(sum, off);
    if (lane == 0) out[OUT_PART + o] = sum + pb[cls];
}

// ---------------- concat logits ----------------
__launch_bounds__(256)
__global__ void concat_kernel(const float* __restrict__ pf, const float* __restrict__ feature,
                              const float* __restrict__ cw, const float* __restrict__ cb,
                              float* __restrict__ out) {
    __shared__ float red[4][16];
    int j = blockIdx.x, tid = threadIdx.x;
    const float* w = cw + (size_t)j*10240;
    float acc[16];
#pragma unroll
    for (int b = 0; b < 16; ++b) acc[b] = 0.f;
    for (int k = tid; k < 10240; k += 256) {
        float wk = w[k];
        const float* v; int stride;
        if (k < 8192) { v = pf + k; stride = 8192; }
        else          { v = feature + (k - 8192); stride = 2048; }
#pragma unroll
        for (int b = 0; b < 16; ++b) acc[b] += v[b*stride] * wk;
    }
#pragma unroll
    for (int b = 0; b < 16; ++b) {
        float s2 = acc[b];
#pragma unroll
        for (int off = 32; off > 0; off >>= 1) s2 += __shfl_down(s2, off);
        if ((tid & 63) == 0) red[tid >> 6][b] = s2;
    }
    __syncthreads();
    if (tid < 16)
        out[OUT_CONCAT + tid*200 + j] = red[0][tid] + red[1][tid] + red[2][tid] + red[3][tid] + cb[j];
}

extern "C" void kernel_launch(void* const* d_in, const int* in_sizes, int n_in,
                              void* d_out, int out_size, void* d_ws, size_t ws_size,
                              hipStream_t stream) {
    const float* x    = (const float*)d_in[0];
    const float* rpn  = (const float*)d_in[1];
    const float* feat = (const float*)d_in[2];
    const float* rout = (const float*)d_in[3];
    const float* d1w  = (const float*)d_in[4];
    const float* d1b  = (const float*)d_in[5];
    const float* d2w  = (const float*)d_in[6];
    const float* d2b  = (const float*)d_in[7];
    const float* d3w  = (const float*)d_in[8];
    const float* d3b  = (const float*)d_in[9];
    const float* t1w  = (const float*)d_in[10];
    const float* t1b  = (const float*)d_in[11];
    const float* t2w  = (const float*)d_in[12];
    const float* t2b  = (const float*)d_in[13];
    const float* t3w  = (const float*)d_in[14];
    const float* t3b  = (const float*)d_in[15];
    const float* fw   = (const float*)d_in[16];
    const float* fbb  = (const float*)d_in[17];
    const float* pw   = (const float*)d_in[18];
    const float* pb   = (const float*)d_in[19];
    const float* cw   = (const float*)d_in[20];
    const float* cb   = (const float*)d_in[21];
    float* out = (float*)d_out;
    float* wsf = (float*)d_ws;
    float* d1  = wsf + OFF_D1;
    float* d2  = wsf + OFF_D2;
    float* d3  = wsf + OFF_D3;
    float* sc  = wsf + OFF_SC;
    float* pfb = wsf + OFF_PF;
    float* P   = wsf + OFF_P;
    int* anc    = (int*)(wsf + OFF_INT);
    int* topidx = anc + NANCH*4;

    // resnet_out passthrough
    hipMemcpyAsync(out, rout, 3200*sizeof(float), hipMemcpyDeviceToDevice, stream);

    anchor_kernel<<<7, 256, 0, stream>>>(anc);

    bool use_mfma = ws_size >= (size_t)TOTAL_MFMA_F * sizeof(float);
    if (use_mfma) {
        unsigned short* ath = (unsigned short*)(wsf + OFF_ATH);
        unsigned short* atl = (unsigned short*)(wsf + OFF_ATL);
        unsigned short* bwh = (unsigned short*)(wsf + OFF_BWH);
        unsigned short* bwl = (unsigned short*)(wsf + OFF_BWL);
        float* pm = wsf + OFF_PM;
        split_rpn_t<<<1024, 256, 0, stream>>>(rpn, ath, atl);
        split_w<<<9216, 256, 0, stream>>>(d1w, bwh, bwl);
        d1_mfma<<<504, 256, 0, stream>>>(ath, atl, bwh, bwl, pm);
        d1_combine<<<(3136*128 + 255)/256, 256, 0, stream>>>(pm, d1b, d1);
    } else {
        float* part = wsf + OFF_BIG;
        conv_d1_part<<<16*16*KSPLIT, 256, 0, stream>>>(rpn, d1w, part);
        d1_reduce<<<(N_D1E + 255)/256, 256, 0, stream>>>(part, d1b, d1);
    }

    // d2/d3 partials reuse the (now dead) d1-staging region
    float* part2 = wsf + OFF_P2;
    float* part3 = wsf + OFF_P3;
    conv_d2_part<<<256, 256, 0, stream>>>(d1, d2w, part2);
    reduce_relu<<<(N_D2E + 255)/256, 256, 0, stream>>>(part2, d2b, d2, 4, N_D2E, 49);
    conv_d3_part<<<256, 256, 0, stream>>>(d2, d3w, part3);
    reduce_relu<<<(N_D3E + 255)/256, 256, 0, stream>>>(part3, d3b, d3, 16, N_D3E, 16);

    tidy_kernel<<<101, 256, 0, stream>>>(d1, d2, d3, t1w, t1b, t2w, t2b, t3w, t3b, sc);
    nms_kernel<<<16, 256, 0, stream>>>(sc, anc, topidx, out);

    if (use_mfma) {
        unsigned short* bfh = (unsigned short*)(wsf + OFF_BFH);
        unsigned short* bfl = (unsigned short*)(wsf + OFF_BFL);
        unsigned short* ph  = (unsigned short*)(wsf + OFF_PH);
        unsigned short* pl  = (unsigned short*)(wsf + OFF_PL);
        split_fw_kernel<<<1280, 256, 0, stream>>>(fw, bfh, bfl);   // PM region dead after d1_combine
        sampler_split_kernel<<<256, 256, 0, stream>>>(x, anc, topidx, ph, pl);
        feat_mfma<<<1024, 256, 0, stream>>>(ph, pl, bfh, bfl, fbb, pfb);
    } else {
        sampler_kernel<<<256, 256, 0, stream>>>(x, anc, topidx, P);
        feat_gemm_kernel<<<512, 256, 0, stream>>>(P, fw, fbb, pfb);
    }

    partcls_kernel<<<12800, 64, 0, stream>>>(pfb, pw, pb, out);
    concat_kernel<<<200, 256, 0, stream>>>(pfb, feat, cw, cb, out);
}